// Round 10
// baseline (527.249 us; speedup 1.0000x reference)
//
#include <hip/hip_runtime.h>
#include <cmath>

// SimplifiedSSM: B=2, L=2048, d_model=768, d_state=16, d_inner=1536
// ROUND 10: register-state scan (no LDS, no shfl). R9's scan was LDS-pipe-bound:
// 8 wave-DS-ops/step (4 reads + 4 shfl) * 1.2e7 = ~124us. Now: thread per
// (b,chunk,d), 16 n-states in VGPRs, coalesced bf16 global loads, float4
// wave-uniform BC loads. Floor: exp pipe (~5us/phase) + streaming (~10us).
#define DMODEL 768
#define DINNER 1536
#define NSTATE 16
#define SEQL   2048
#define LDSS   56      // GEMM LDS row stride in shorts (112B: 16B-aligned rows)
#define NCHUNK 32
#define CHLEN  64      // SEQL / NCHUNK

#define DT_F32  0
#define DT_BF16 1
#define DT_ZERO 2

typedef __bf16 bf16x8 __attribute__((ext_vector_type(8)));
typedef float  f32x4  __attribute__((ext_vector_type(4)));

__device__ __forceinline__ float bf2f(unsigned short h) {
    union { unsigned u; float f; } v; v.u = ((unsigned)h) << 16; return v.f;
}
__device__ __forceinline__ unsigned short f2bf(float f) {
    union { float f; unsigned u; } v; v.f = f;
    unsigned r = (v.u + 0x7FFFu + ((v.u >> 16) & 1u)) >> 16;
    return (unsigned short)r;
}
__device__ int detect_dtype(const void* p) {
    const unsigned* u = (const unsigned*)p;
    int nzlo = 0, band = 0, anynz = 0;
    for (int i = 0; i < 64; ++i) {
        unsigned w = u[i];
        anynz |= (w != 0);
        unsigned lo = w & 0xFFFFu;
        if (lo) {
            ++nzlo;
            unsigned e8 = (lo >> 7) & 0xFF;
            if (e8 >= 0x60 && e8 <= 0x8E) ++band;
        }
    }
    if (nzlo >= 8) return (band * 2 > nzlo) ? DT_BF16 : DT_F32;
    return anynz ? DT_F32 : DT_ZERO;
}
__device__ __forceinline__ float LD(const void* p, size_t i, int dt) {
    if (dt == DT_BF16) return bf2f(((const unsigned short*)p)[i]);
    if (dt == DT_F32)  return ((const float*)p)[i];
    return 0.f;
}

// ---- x -> bf16 ----
__global__ __launch_bounds__(256) void cvt_x_kernel(
    const void* __restrict__ x, unsigned short* __restrict__ xb)
{
    __shared__ int s_dt;
    if (threadIdx.x == 0) s_dt = detect_dtype(x);
    __syncthreads();
    const int dt = s_dt;
    size_t i = ((size_t)blockIdx.x * 256 + threadIdx.x) * 4;
    ushort4 o;
    o.x = f2bf(LD(x, i + 0, dt)); o.y = f2bf(LD(x, i + 1, dt));
    o.z = f2bf(LD(x, i + 2, dt)); o.w = f2bf(LD(x, i + 3, dt));
    *(ushort4*)&xb[i] = o;
}

// ---- small params -> f32 ----
__global__ __launch_bounds__(256) void cvt_params_kernel(
    const void* cw, const void* cb, const void* db, const void* Al,
    const void* Dv, const void* xp, float* __restrict__ out)
{
    __shared__ int dts[6];
    if (threadIdx.x == 0) {
        dts[0] = detect_dtype(cw); dts[1] = detect_dtype(cb);
        dts[2] = detect_dtype(db); dts[3] = detect_dtype(Al);
        dts[4] = detect_dtype(Dv); dts[5] = detect_dtype(xp);
    }
    __syncthreads();
    int g = blockIdx.x * 256 + threadIdx.x;
    if (g >= 82944) return;
    const void* src; int local; int which;
    if      (g <  4608) { src = cw; local = g;         which = 0; }
    else if (g <  6144) { src = cb; local = g - 4608;  which = 1; }
    else if (g <  7680) { src = db; local = g - 6144;  which = 2; }
    else if (g < 32256) { src = Al; local = g - 7680;  which = 3; }
    else if (g < 33792) { src = Dv; local = g - 32256; which = 4; }
    else                { src = xp; local = g - 33792; which = 5; }
    out[g] = LD(src, local, dts[which]);
}

// ---- transpose: in[R][C] -> out[C][R] bf16 ----
__global__ __launch_bounds__(256) void transpose_any(
    const void* __restrict__ in, unsigned short* __restrict__ out, int R, int C)
{
    __shared__ unsigned short tile[32][33];
    __shared__ int s_dt;
    if (threadIdx.x == 0) s_dt = detect_dtype(in);
    __syncthreads();
    const int dt = s_dt;
    const int t = threadIdx.x;
    const int tx = t & 31, ty = t >> 5;
    const int bx = blockIdx.x * 32, by = blockIdx.y * 32;
    #pragma unroll
    for (int i = 0; i < 4; ++i) {
        int r = by + ty + i * 8;
        tile[ty + i * 8][tx] = f2bf(LD(in, (size_t)r * C + bx + tx, dt));
    }
    __syncthreads();
    #pragma unroll
    for (int i = 0; i < 4; ++i) {
        int c = bx + ty + i * 8;
        out[(size_t)c * R + by + tx] = tile[tx][ty + i * 8];
    }
}

// ---- MFMA GEMM: C = A[M][K] @ Bt[N][K]^T ----
// EPI 1: bf16 C0 = softplus(v + biasf[col])
// EPI 2: f32  C0 = v (final output)
// EPI 3: col < N/2 -> bf16 C0 = v ; else bf16 C1 = silu(v)
template<int EPI>
__global__ __launch_bounds__(256) void gemm_kernel(
    const unsigned short* __restrict__ A, const unsigned short* __restrict__ Bt,
    void* __restrict__ C0, void* __restrict__ C1, const float* __restrict__ biasf,
    int M, int N, int K)
{
    __shared__ __align__(16) unsigned short As[128 * LDSS];
    __shared__ __align__(16) unsigned short Bs[128 * LDSS];
    const int t    = threadIdx.x;
    const int m0   = blockIdx.x * 128;
    const int n0   = blockIdx.y * 128;
    const int w    = t >> 6;
    const int lane = t & 63;
    const int wm   = (w >> 1) * 64, wn = (w & 1) * 64;
    const int lm   = lane & 15, quad = lane >> 4;

    f32x4 acc[4][4] = {};

    for (int k0 = 0; k0 < K; k0 += 32) {
        #pragma unroll
        for (int i = 0; i < 2; ++i) {
            int id = t + i * 256;
            int r = id >> 2, c = (id & 3) * 8;
            *(uint4*)&As[r * LDSS + c] = *(const uint4*)&A[(size_t)(m0 + r) * K + k0 + c];
            *(uint4*)&Bs[r * LDSS + c] = *(const uint4*)&Bt[(size_t)(n0 + r) * K + k0 + c];
        }
        __syncthreads();
        bf16x8 af[4], bfr[4];
        #pragma unroll
        for (int i = 0; i < 4; ++i)
            af[i] = *(const bf16x8*)&As[(wm + i * 16 + lm) * LDSS + quad * 8];
        #pragma unroll
        for (int j = 0; j < 4; ++j)
            bfr[j] = *(const bf16x8*)&Bs[(wn + j * 16 + lm) * LDSS + quad * 8];
        #pragma unroll
        for (int i = 0; i < 4; ++i)
            #pragma unroll
            for (int j = 0; j < 4; ++j)
                acc[i][j] = __builtin_amdgcn_mfma_f32_16x16x32_bf16(af[i], bfr[j], acc[i][j], 0, 0, 0);
        __syncthreads();
    }

    const int half = N >> 1;
    #pragma unroll
    for (int i = 0; i < 4; ++i) {
        #pragma unroll
        for (int j = 0; j < 4; ++j) {
            int col = n0 + wn + j * 16 + lm;
            #pragma unroll
            for (int r = 0; r < 4; ++r) {
                int row = m0 + wm + i * 16 + quad * 4 + r;
                float v = acc[i][j][r];
                if (EPI == 1) {
                    v += biasf[col];
                    float sp = (v > 20.f) ? v : log1pf(__expf(v));
                    ((unsigned short*)C0)[(size_t)row * N + col] = f2bf(sp);
                } else if (EPI == 2) {
                    ((float*)C0)[(size_t)row * N + col] = v;
                } else {
                    if (col < half) {
                        ((unsigned short*)C0)[(size_t)row * half + col] = f2bf(v);
                    } else {
                        float s = v / (1.f + __expf(-v));
                        ((unsigned short*)C1)[(size_t)row * half + col - half] = f2bf(s);
                    }
                }
            }
        }
    }
}

// ---- depthwise conv3 + bias + SiLU ----
__global__ __launch_bounds__(256) void conv_silu_kernel(
    const unsigned short* __restrict__ xcpre, const float* __restrict__ cwf,
    const float* __restrict__ cbf, unsigned short* __restrict__ xcb)
{
    int idx = blockIdx.x * 256 + threadIdx.x;
    int d   = idx % DINNER;
    int row = idx / DINNER;
    int l   = row % SEQL;
    size_t base = (size_t)row * DINNER + d;
    float acc = cbf[d];
    if (l > 0)        acc += bf2f(xcpre[base - DINNER]) * cwf[d * 3 + 0];
    acc += bf2f(xcpre[base]) * cwf[d * 3 + 1];
    if (l < SEQL - 1) acc += bf2f(xcpre[base + DINNER]) * cwf[d * 3 + 2];
    float s = acc / (1.f + __expf(-acc));
    xcb[base] = f2bf(s);
}

// ---- x_proj: BC[row][32] = xc[row][:] @ xproj_f[1536][32] ----
__global__ __launch_bounds__(128) void xproj_kernel(
    const unsigned short* __restrict__ xcb, const float* __restrict__ wf,
    float* __restrict__ BC)
{
    __shared__ float red[4][32][4];
    const int t = threadIdx.x;
    const int s = t & 31, part = t >> 5;
    const int row0 = blockIdx.x * 4;
    float acc[4] = {0.f, 0.f, 0.f, 0.f};
    for (int k = part * 384; k < (part + 1) * 384; ++k) {
        float wv = wf[k * 32 + s];
        #pragma unroll
        for (int r = 0; r < 4; ++r)
            acc[r] += bf2f(xcb[(size_t)(row0 + r) * DINNER + k]) * wv;
    }
    #pragma unroll
    for (int r = 0; r < 4; ++r) red[part][s][r] = acc[r];
    __syncthreads();
    if (t < 32) {
        #pragma unroll
        for (int r = 0; r < 4; ++r)
            BC[(size_t)(row0 + r) * 32 + t] =
                red[0][t][r] + red[1][t][r] + red[2][t][r] + red[3][t][r];
    }
}

// ================= register-state chunked scan =================
// h_t = a_t h_{t-1} + u_t ; a = exp(delta*A), u = delta*xc*B.
// Thread = (b, chunk, d): all 16 n-states in VGPRs. No LDS, no shfl.
// P[n] = exp(A_n * sum(dv)) (bf16), S = chunk-local final h (f32), [b][c][d][n].

// Phase A. 98304 threads = 384 blocks.
__global__ __launch_bounds__(256) void scan_phase_a(
    const unsigned short* __restrict__ dlt, const unsigned short* __restrict__ xcb,
    const float* __restrict__ BC, const float* __restrict__ A_log_f,
    unsigned short* __restrict__ P, float* __restrict__ S)
{
    int g = blockIdx.x * 256 + threadIdx.x;
    int d = g % DINNER;
    int c = (g / DINNER) % NCHUNK;
    int b = g / (DINNER * NCHUNK);
    float A[16], h[16];
    #pragma unroll
    for (int n = 0; n < 16; ++n) {
        A[n] = -__expf(A_log_f[d * 16 + n]);
        h[n] = 0.f;
    }
    float sdv = 0.f;
    const int row0 = b * SEQL + c * CHLEN;
    for (int l = 0; l < CHLEN; ++l) {
        size_t row = (size_t)(row0 + l);
        float dv = bf2f(dlt[row * DINNER + d]);
        float xv = bf2f(xcb[row * DINNER + d]);
        float dx = dv * xv;
        sdv += dv;
        const f32x4* bc4 = (const f32x4*)&BC[row * 32];
        float Bv[16];
        *(f32x4*)&Bv[0] = bc4[0]; *(f32x4*)&Bv[4]  = bc4[1];
        *(f32x4*)&Bv[8] = bc4[2]; *(f32x4*)&Bv[12] = bc4[3];
        #pragma unroll
        for (int n = 0; n < 16; ++n) {
            float a = __expf(dv * A[n]);
            h[n] = a * h[n] + dx * Bv[n];
        }
    }
    size_t idx = (((size_t)(b * NCHUNK + c)) * DINNER + d) * 16;
    #pragma unroll
    for (int n = 0; n < 16; ++n) {
        P[idx + n] = f2bf(__expf(sdv * A[n]));
        S[idx + n] = h[n];
    }
}

// Phase B: serial combine over chunks; writes Hin into S in place.
__global__ __launch_bounds__(256) void scan_combine(
    const unsigned short* __restrict__ P, float* __restrict__ S)
{
    int t = blockIdx.x * 256 + threadIdx.x;            // < 2*1536*16
    int b = t / (DINNER * NSTATE);
    int dn = t % (DINNER * NSTATE);
    float H = 0.f;
    for (int c = 0; c < NCHUNK; ++c) {
        size_t idx = ((size_t)(b * NCHUNK + c)) * (DINNER * NSTATE) + dn;
        float Pv = bf2f(P[idx]);
        float Sv = S[idx];
        S[idx] = H;                 // Hin for chunk c
        H = Pv * H + Sv;
    }
}

// Phase C: replay chunk from Hin(=S); y = sum_n h*C in registers;
// D-skip + silu(z) gate -> yg bf16.
__global__ __launch_bounds__(256) void scan_phase_c(
    const unsigned short* __restrict__ dlt, const unsigned short* __restrict__ xcb,
    const float* __restrict__ BC, const unsigned short* __restrict__ zg,
    const float* __restrict__ A_log_f, const float* __restrict__ D_f,
    const float* __restrict__ Hin, unsigned short* __restrict__ yg)
{
    int g = blockIdx.x * 256 + threadIdx.x;
    int d = g % DINNER;
    int c = (g / DINNER) % NCHUNK;
    int b = g / (DINNER * NCHUNK);
    float A[16], h[16];
    size_t hidx = (((size_t)(b * NCHUNK + c)) * DINNER + d) * 16;
    #pragma unroll
    for (int n = 0; n < 16; ++n) A[n] = -__expf(A_log_f[d * 16 + n]);
    #pragma unroll
    for (int n = 0; n < 16; ++n) h[n] = Hin[hidx + n];
    const float Dd = D_f[d];
    const int row0 = b * SEQL + c * CHLEN;
    for (int l = 0; l < CHLEN; ++l) {
        size_t row = (size_t)(row0 + l);
        float dv = bf2f(dlt[row * DINNER + d]);
        float xv = bf2f(xcb[row * DINNER + d]);
        float zv = bf2f(zg[row * DINNER + d]);
        float dx = dv * xv;
        const f32x4* bc4 = (const f32x4*)&BC[row * 32];
        float Bv[16], Cv[16];
        *(f32x4*)&Bv[0] = bc4[0]; *(f32x4*)&Bv[4]  = bc4[1];
        *(f32x4*)&Bv[8] = bc4[2]; *(f32x4*)&Bv[12] = bc4[3];
        *(f32x4*)&Cv[0] = bc4[4]; *(f32x4*)&Cv[4]  = bc4[5];
        *(f32x4*)&Cv[8] = bc4[6]; *(f32x4*)&Cv[12] = bc4[7];
        float y = 0.f;
        #pragma unroll
        for (int n = 0; n < 16; ++n) {
            float a = __expf(dv * A[n]);
            h[n] = a * h[n] + dx * Bv[n];
            y += h[n] * Cv[n];
        }
        yg[row * DINNER + d] = f2bf((y + Dd * xv) * zv);
    }
}

__global__ void guard_kernel(float* out, int code)
{
    if (threadIdx.x == 0 && blockIdx.x == 0 && code) out[0] = (float)code;
}

extern "C" void kernel_launch(void* const* d_in, const int* in_sizes, int n_in,
                              void* d_out, int out_size, void* d_ws, size_t ws_size,
                              hipStream_t stream) {
    static const int EXPECTED[10] = {3145728, 2359296, 4608, 1536, 49152,
                                     2359296, 1536, 24576, 1536, 1179648};
    bool ok = (n_in == 10);
    if (ok) for (int i = 0; i < 10; ++i) ok = ok && (in_sizes[i] == EXPECTED[i]);
    int code = 0;
    if (!ok) code = 2000;
    else if (ws_size < 67895296ULL) code = 3000;   // R5 proved ws_size >= 76021760
    if (code) { guard_kernel<<<1, 64, 0, stream>>>((float*)d_out, code); return; }

    const void* x       = d_in[0];
    const void* in_w    = d_in[1];
    const void* conv_w  = d_in[2];
    const void* conv_b  = d_in[3];
    const void* xproj_w = d_in[4];
    const void* dt_w    = d_in[5];
    const void* dt_b    = d_in[6];
    const void* A_log   = d_in[7];
    const void* Dvec    = d_in[8];
    const void* out_w   = d_in[9];

    char* ws = (char*)d_ws;
    float* conv_w_f = (float*)(ws + 0);        // 4608
    float* conv_b_f = (float*)(ws + 18432);    // 1536
    float* dt_b_f   = (float*)(ws + 24576);    // 1536
    float* A_log_f  = (float*)(ws + 30720);    // 24576
    float* D_f      = (float*)(ws + 129024);   // 1536
    float* xproj_f  = (float*)(ws + 135168);   // 49152
    unsigned short* xb    = (unsigned short*)(ws + 524288);    // [4096][768]  (dead after gemm1)
    unsigned short* inT   = (unsigned short*)(ws + 6815744);   // [3072][768]  (dead after gemm1)
    unsigned short* yg    = (unsigned short*)(ws + 524288);    // [4096][1536] alias xb+inT
    unsigned short* dtT   = (unsigned short*)(ws + 13107200);  // [1536][1536]
    unsigned short* outT  = (unsigned short*)(ws + 17825792);  // [768][1536]
    unsigned short* xcpre = (unsigned short*)(ws + 20185088);  // [4096][1536] (dead after conv)
    unsigned short* dlt   = xcpre;                             // alias (gemm2 out)
    float*          BC    = (float*)(ws + 32768000);           // [4096][32]
    unsigned short* zg    = (unsigned short*)(ws + 33292288);  // [4096][1536] silu(z)
    unsigned short* xcb   = (unsigned short*)(ws + 45875200);  // [4096][1536]
    // scan summaries beyond the R9 footprint (ws_size >= 76021760 proven in R5)
    float*          scanS = (float*)(ws + 58458112);           // [2][32][1536][16] f32 6.29MB
    unsigned short* scanP = (unsigned short*)(ws + 64749568);  // same shape bf16   3.15MB
                                                               // high-water 67895296

    cvt_params_kernel<<<324, 256, 0, stream>>>(conv_w, conv_b, dt_b, A_log, Dvec, xproj_w,
                                               (float*)ws);
    cvt_x_kernel<<<3072, 256, 0, stream>>>(x, xb);
    transpose_any<<<dim3(3072 / 32, 768 / 32), 256, 0, stream>>>(in_w, inT, 768, 3072);
    transpose_any<<<dim3(1536 / 32, 1536 / 32), 256, 0, stream>>>(dt_w, dtT, 1536, 1536);
    transpose_any<<<dim3(768 / 32, 1536 / 32), 256, 0, stream>>>(out_w, outT, 1536, 768);

    gemm_kernel<3><<<dim3(32, 24), 256, 0, stream>>>(xb, inT, (void*)xcpre, (void*)zg,
                                                     nullptr, 4096, 3072, 768);
    conv_silu_kernel<<<(4096 * DINNER) / 256, 256, 0, stream>>>(xcpre, conv_w_f, conv_b_f, xcb);
    xproj_kernel<<<1024, 128, 0, stream>>>(xcb, xproj_f, BC);
    gemm_kernel<1><<<dim3(32, 12), 256, 0, stream>>>(xcb, dtT, (void*)dlt, nullptr,
                                                     dt_b_f, 4096, 1536, 1536);
    // register-state chunked scan
    scan_phase_a<<<384, 256, 0, stream>>>(dlt, xcb, BC, A_log_f, scanP, scanS);
    scan_combine<<<192, 256, 0, stream>>>(scanP, scanS);
    scan_phase_c<<<384, 256, 0, stream>>>(dlt, xcb, BC, zg, A_log_f, D_f, scanS, yg);
    gemm_kernel<2><<<dim3(32, 6), 256, 0, stream>>>(yg, outT, d_out, nullptr,
                                                    nullptr, 4096, 768, 1536);
}

// Round 11
// 436.073 us; speedup vs baseline: 1.2091x; 1.2091x over previous
//
#include <hip/hip_runtime.h>
#include <cmath>

// SimplifiedSSM: B=2, L=2048, d_model=768, d_state=16, d_inner=1536
// ROUND 11: fix R10's scratch spill (VGPR_Count=36 proved h/A/B/C arrays were
// spilled: reinterpret-cast stores into float[16] defeated SROA). All per-thread
// state is now f32x4 vector variables assigned by value -> registers.
#define DMODEL 768
#define DINNER 1536
#define NSTATE 16
#define SEQL   2048
#define LDSS   56      // GEMM LDS row stride in shorts (112B: 16B-aligned rows)
#define NCHUNK 32
#define CHLEN  64      // SEQL / NCHUNK

#define DT_F32  0
#define DT_BF16 1
#define DT_ZERO 2

typedef __bf16 bf16x8 __attribute__((ext_vector_type(8)));
typedef float  f32x4  __attribute__((ext_vector_type(4)));

__device__ __forceinline__ float bf2f(unsigned short h) {
    union { unsigned u; float f; } v; v.u = ((unsigned)h) << 16; return v.f;
}
__device__ __forceinline__ unsigned short f2bf(float f) {
    union { float f; unsigned u; } v; v.f = f;
    unsigned r = (v.u + 0x7FFFu + ((v.u >> 16) & 1u)) >> 16;
    return (unsigned short)r;
}
__device__ int detect_dtype(const void* p) {
    const unsigned* u = (const unsigned*)p;
    int nzlo = 0, band = 0, anynz = 0;
    for (int i = 0; i < 64; ++i) {
        unsigned w = u[i];
        anynz |= (w != 0);
        unsigned lo = w & 0xFFFFu;
        if (lo) {
            ++nzlo;
            unsigned e8 = (lo >> 7) & 0xFF;
            if (e8 >= 0x60 && e8 <= 0x8E) ++band;
        }
    }
    if (nzlo >= 8) return (band * 2 > nzlo) ? DT_BF16 : DT_F32;
    return anynz ? DT_F32 : DT_ZERO;
}
__device__ __forceinline__ float LD(const void* p, size_t i, int dt) {
    if (dt == DT_BF16) return bf2f(((const unsigned short*)p)[i]);
    if (dt == DT_F32)  return ((const float*)p)[i];
    return 0.f;
}

// ---- x -> bf16 ----
__global__ __launch_bounds__(256) void cvt_x_kernel(
    const void* __restrict__ x, unsigned short* __restrict__ xb)
{
    __shared__ int s_dt;
    if (threadIdx.x == 0) s_dt = detect_dtype(x);
    __syncthreads();
    const int dt = s_dt;
    size_t i = ((size_t)blockIdx.x * 256 + threadIdx.x) * 4;
    ushort4 o;
    o.x = f2bf(LD(x, i + 0, dt)); o.y = f2bf(LD(x, i + 1, dt));
    o.z = f2bf(LD(x, i + 2, dt)); o.w = f2bf(LD(x, i + 3, dt));
    *(ushort4*)&xb[i] = o;
}

// ---- small params -> f32 ----
__global__ __launch_bounds__(256) void cvt_params_kernel(
    const void* cw, const void* cb, const void* db, const void* Al,
    const void* Dv, const void* xp, float* __restrict__ out)
{
    __shared__ int dts[6];
    if (threadIdx.x == 0) {
        dts[0] = detect_dtype(cw); dts[1] = detect_dtype(cb);
        dts[2] = detect_dtype(db); dts[3] = detect_dtype(Al);
        dts[4] = detect_dtype(Dv); dts[5] = detect_dtype(xp);
    }
    __syncthreads();
    int g = blockIdx.x * 256 + threadIdx.x;
    if (g >= 82944) return;
    const void* src; int local; int which;
    if      (g <  4608) { src = cw; local = g;         which = 0; }
    else if (g <  6144) { src = cb; local = g - 4608;  which = 1; }
    else if (g <  7680) { src = db; local = g - 6144;  which = 2; }
    else if (g < 32256) { src = Al; local = g - 7680;  which = 3; }
    else if (g < 33792) { src = Dv; local = g - 32256; which = 4; }
    else                { src = xp; local = g - 33792; which = 5; }
    out[g] = LD(src, local, dts[which]);
}

// ---- transpose: in[R][C] -> out[C][R] bf16 ----
__global__ __launch_bounds__(256) void transpose_any(
    const void* __restrict__ in, unsigned short* __restrict__ out, int R, int C)
{
    __shared__ unsigned short tile[32][33];
    __shared__ int s_dt;
    if (threadIdx.x == 0) s_dt = detect_dtype(in);
    __syncthreads();
    const int dt = s_dt;
    const int t = threadIdx.x;
    const int tx = t & 31, ty = t >> 5;
    const int bx = blockIdx.x * 32, by = blockIdx.y * 32;
    #pragma unroll
    for (int i = 0; i < 4; ++i) {
        int r = by + ty + i * 8;
        tile[ty + i * 8][tx] = f2bf(LD(in, (size_t)r * C + bx + tx, dt));
    }
    __syncthreads();
    #pragma unroll
    for (int i = 0; i < 4; ++i) {
        int c = bx + ty + i * 8;
        out[(size_t)c * R + by + tx] = tile[tx][ty + i * 8];
    }
}

// ---- MFMA GEMM: C = A[M][K] @ Bt[N][K]^T ----
// EPI 1: bf16 C0 = softplus(v + biasf[col])
// EPI 2: f32  C0 = v (final output)
// EPI 3: col < N/2 -> bf16 C0 = v ; else bf16 C1 = silu(v)
template<int EPI>
__global__ __launch_bounds__(256) void gemm_kernel(
    const unsigned short* __restrict__ A, const unsigned short* __restrict__ Bt,
    void* __restrict__ C0, void* __restrict__ C1, const float* __restrict__ biasf,
    int M, int N, int K)
{
    __shared__ __align__(16) unsigned short As[128 * LDSS];
    __shared__ __align__(16) unsigned short Bs[128 * LDSS];
    const int t    = threadIdx.x;
    const int m0   = blockIdx.x * 128;
    const int n0   = blockIdx.y * 128;
    const int w    = t >> 6;
    const int lane = t & 63;
    const int wm   = (w >> 1) * 64, wn = (w & 1) * 64;
    const int lm   = lane & 15, quad = lane >> 4;

    f32x4 acc[4][4] = {};

    for (int k0 = 0; k0 < K; k0 += 32) {
        #pragma unroll
        for (int i = 0; i < 2; ++i) {
            int id = t + i * 256;
            int r = id >> 2, c = (id & 3) * 8;
            *(uint4*)&As[r * LDSS + c] = *(const uint4*)&A[(size_t)(m0 + r) * K + k0 + c];
            *(uint4*)&Bs[r * LDSS + c] = *(const uint4*)&Bt[(size_t)(n0 + r) * K + k0 + c];
        }
        __syncthreads();
        bf16x8 af[4], bfr[4];
        #pragma unroll
        for (int i = 0; i < 4; ++i)
            af[i] = *(const bf16x8*)&As[(wm + i * 16 + lm) * LDSS + quad * 8];
        #pragma unroll
        for (int j = 0; j < 4; ++j)
            bfr[j] = *(const bf16x8*)&Bs[(wn + j * 16 + lm) * LDSS + quad * 8];
        #pragma unroll
        for (int i = 0; i < 4; ++i)
            #pragma unroll
            for (int j = 0; j < 4; ++j)
                acc[i][j] = __builtin_amdgcn_mfma_f32_16x16x32_bf16(af[i], bfr[j], acc[i][j], 0, 0, 0);
        __syncthreads();
    }

    const int half = N >> 1;
    #pragma unroll
    for (int i = 0; i < 4; ++i) {
        #pragma unroll
        for (int j = 0; j < 4; ++j) {
            int col = n0 + wn + j * 16 + lm;
            #pragma unroll
            for (int r = 0; r < 4; ++r) {
                int row = m0 + wm + i * 16 + quad * 4 + r;
                float v = acc[i][j][r];
                if (EPI == 1) {
                    v += biasf[col];
                    float sp = (v > 20.f) ? v : log1pf(__expf(v));
                    ((unsigned short*)C0)[(size_t)row * N + col] = f2bf(sp);
                } else if (EPI == 2) {
                    ((float*)C0)[(size_t)row * N + col] = v;
                } else {
                    if (col < half) {
                        ((unsigned short*)C0)[(size_t)row * half + col] = f2bf(v);
                    } else {
                        float s = v / (1.f + __expf(-v));
                        ((unsigned short*)C1)[(size_t)row * half + col - half] = f2bf(s);
                    }
                }
            }
        }
    }
}

// ---- depthwise conv3 + bias + SiLU ----
__global__ __launch_bounds__(256) void conv_silu_kernel(
    const unsigned short* __restrict__ xcpre, const float* __restrict__ cwf,
    const float* __restrict__ cbf, unsigned short* __restrict__ xcb)
{
    int idx = blockIdx.x * 256 + threadIdx.x;
    int d   = idx % DINNER;
    int row = idx / DINNER;
    int l   = row % SEQL;
    size_t base = (size_t)row * DINNER + d;
    float acc = cbf[d];
    if (l > 0)        acc += bf2f(xcpre[base - DINNER]) * cwf[d * 3 + 0];
    acc += bf2f(xcpre[base]) * cwf[d * 3 + 1];
    if (l < SEQL - 1) acc += bf2f(xcpre[base + DINNER]) * cwf[d * 3 + 2];
    float s = acc / (1.f + __expf(-acc));
    xcb[base] = f2bf(s);
}

// ---- x_proj: BC[row][32] = xc[row][:] @ xproj_f[1536][32] ----
__global__ __launch_bounds__(128) void xproj_kernel(
    const unsigned short* __restrict__ xcb, const float* __restrict__ wf,
    float* __restrict__ BC)
{
    __shared__ float red[4][32][4];
    const int t = threadIdx.x;
    const int s = t & 31, part = t >> 5;
    const int row0 = blockIdx.x * 4;
    float acc[4] = {0.f, 0.f, 0.f, 0.f};
    for (int k = part * 384; k < (part + 1) * 384; ++k) {
        float wv = wf[k * 32 + s];
        #pragma unroll
        for (int r = 0; r < 4; ++r)
            acc[r] += bf2f(xcb[(size_t)(row0 + r) * DINNER + k]) * wv;
    }
    #pragma unroll
    for (int r = 0; r < 4; ++r) red[part][s][r] = acc[r];
    __syncthreads();
    if (t < 32) {
        #pragma unroll
        for (int r = 0; r < 4; ++r)
            BC[(size_t)(row0 + r) * 32 + t] =
                red[0][t][r] + red[1][t][r] + red[2][t][r] + red[3][t][r];
    }
}

// ================= register-state chunked scan (spill-free) =================
// h_t = a_t h_{t-1} + u_t ; a = exp(delta*A), u = delta*xc*B.
// Thread = (b, chunk, d): 16 n-states in 4 f32x4 vector registers.
// P[n] = exp(A_n * sum(dv)) (bf16), S = chunk-local final h (f32), [b][c][d][n].

// Phase A. 98304 threads = 384 blocks.
__global__ __launch_bounds__(256) void scan_phase_a(
    const unsigned short* __restrict__ dlt, const unsigned short* __restrict__ xcb,
    const float* __restrict__ BC, const float* __restrict__ A_log_f,
    unsigned short* __restrict__ P, float* __restrict__ S)
{
    int g = blockIdx.x * 256 + threadIdx.x;
    int d = g % DINNER;
    int c = (g / DINNER) % NCHUNK;
    int b = g / (DINNER * NCHUNK);
    f32x4 A4[4], h4[4];
    const f32x4* al4 = (const f32x4*)&A_log_f[d * 16];
    #pragma unroll
    for (int q = 0; q < 4; ++q) {
        f32x4 al = al4[q];
        f32x4 a;
        a[0] = -__expf(al[0]); a[1] = -__expf(al[1]);
        a[2] = -__expf(al[2]); a[3] = -__expf(al[3]);
        A4[q] = a;
        h4[q] = (f32x4){0.f, 0.f, 0.f, 0.f};
    }
    float sdv = 0.f;
    const int row0 = b * SEQL + c * CHLEN;
    for (int l = 0; l < CHLEN; ++l) {
        size_t row = (size_t)(row0 + l);
        float dv = bf2f(dlt[row * DINNER + d]);
        float xv = bf2f(xcb[row * DINNER + d]);
        float dx = dv * xv;
        sdv += dv;
        const f32x4* bc4 = (const f32x4*)&BC[row * 32];
        #pragma unroll
        for (int q = 0; q < 4; ++q) {
            f32x4 Bq = bc4[q];
            f32x4 e;
            e[0] = __expf(dv * A4[q][0]); e[1] = __expf(dv * A4[q][1]);
            e[2] = __expf(dv * A4[q][2]); e[3] = __expf(dv * A4[q][3]);
            h4[q] = e * h4[q] + dx * Bq;
        }
    }
    size_t idx = (((size_t)(b * NCHUNK + c)) * DINNER + d) * 16;
    #pragma unroll
    for (int q = 0; q < 4; ++q) {
        *(f32x4*)&S[idx + q * 4] = h4[q];
        ushort4 pq;
        pq.x = f2bf(__expf(sdv * A4[q][0]));
        pq.y = f2bf(__expf(sdv * A4[q][1]));
        pq.z = f2bf(__expf(sdv * A4[q][2]));
        pq.w = f2bf(__expf(sdv * A4[q][3]));
        *(ushort4*)&P[idx + q * 4] = pq;
    }
}

// Phase B: serial combine over chunks; writes Hin into S in place.
__global__ __launch_bounds__(256) void scan_combine(
    const unsigned short* __restrict__ P, float* __restrict__ S)
{
    int t = blockIdx.x * 256 + threadIdx.x;            // < 2*1536*16
    int b = t / (DINNER * NSTATE);
    int dn = t % (DINNER * NSTATE);
    float H = 0.f;
    for (int c = 0; c < NCHUNK; ++c) {
        size_t idx = ((size_t)(b * NCHUNK + c)) * (DINNER * NSTATE) + dn;
        float Pv = bf2f(P[idx]);
        float Sv = S[idx];
        S[idx] = H;                 // Hin for chunk c
        H = Pv * H + Sv;
    }
}

// Phase C: replay chunk from Hin(=S); y = sum_n h*C in registers;
// D-skip + silu(z) gate -> yg bf16.
__global__ __launch_bounds__(256) void scan_phase_c(
    const unsigned short* __restrict__ dlt, const unsigned short* __restrict__ xcb,
    const float* __restrict__ BC, const unsigned short* __restrict__ zg,
    const float* __restrict__ A_log_f, const float* __restrict__ D_f,
    const float* __restrict__ Hin, unsigned short* __restrict__ yg)
{
    int g = blockIdx.x * 256 + threadIdx.x;
    int d = g % DINNER;
    int c = (g / DINNER) % NCHUNK;
    int b = g / (DINNER * NCHUNK);
    f32x4 A4[4], h4[4];
    const f32x4* al4 = (const f32x4*)&A_log_f[d * 16];
    size_t hidx = (((size_t)(b * NCHUNK + c)) * DINNER + d) * 16;
    const f32x4* hin4 = (const f32x4*)&Hin[hidx];
    #pragma unroll
    for (int q = 0; q < 4; ++q) {
        f32x4 al = al4[q];
        f32x4 a;
        a[0] = -__expf(al[0]); a[1] = -__expf(al[1]);
        a[2] = -__expf(al[2]); a[3] = -__expf(al[3]);
        A4[q] = a;
        h4[q] = hin4[q];
    }
    const float Dd = D_f[d];
    const int row0 = b * SEQL + c * CHLEN;
    for (int l = 0; l < CHLEN; ++l) {
        size_t row = (size_t)(row0 + l);
        float dv = bf2f(dlt[row * DINNER + d]);
        float xv = bf2f(xcb[row * DINNER + d]);
        float zv = bf2f(zg[row * DINNER + d]);
        float dx = dv * xv;
        const f32x4* bc4 = (const f32x4*)&BC[row * 32];
        f32x4 yv = (f32x4){0.f, 0.f, 0.f, 0.f};
        #pragma unroll
        for (int q = 0; q < 4; ++q) {
            f32x4 Bq = bc4[q];
            f32x4 Cq = bc4[4 + q];
            f32x4 e;
            e[0] = __expf(dv * A4[q][0]); e[1] = __expf(dv * A4[q][1]);
            e[2] = __expf(dv * A4[q][2]); e[3] = __expf(dv * A4[q][3]);
            h4[q] = e * h4[q] + dx * Bq;
            yv = yv + h4[q] * Cq;
        }
        float y = yv[0] + yv[1] + yv[2] + yv[3];
        yg[row * DINNER + d] = f2bf((y + Dd * xv) * zv);
    }
}

__global__ void guard_kernel(float* out, int code)
{
    if (threadIdx.x == 0 && blockIdx.x == 0 && code) out[0] = (float)code;
}

extern "C" void kernel_launch(void* const* d_in, const int* in_sizes, int n_in,
                              void* d_out, int out_size, void* d_ws, size_t ws_size,
                              hipStream_t stream) {
    static const int EXPECTED[10] = {3145728, 2359296, 4608, 1536, 49152,
                                     2359296, 1536, 24576, 1536, 1179648};
    bool ok = (n_in == 10);
    if (ok) for (int i = 0; i < 10; ++i) ok = ok && (in_sizes[i] == EXPECTED[i]);
    int code = 0;
    if (!ok) code = 2000;
    else if (ws_size < 67895296ULL) code = 3000;   // R5 proved ws_size >= 76021760
    if (code) { guard_kernel<<<1, 64, 0, stream>>>((float*)d_out, code); return; }

    const void* x       = d_in[0];
    const void* in_w    = d_in[1];
    const void* conv_w  = d_in[2];
    const void* conv_b  = d_in[3];
    const void* xproj_w = d_in[4];
    const void* dt_w    = d_in[5];
    const void* dt_b    = d_in[6];
    const void* A_log   = d_in[7];
    const void* Dvec    = d_in[8];
    const void* out_w   = d_in[9];

    char* ws = (char*)d_ws;
    float* conv_w_f = (float*)(ws + 0);        // 4608
    float* conv_b_f = (float*)(ws + 18432);    // 1536
    float* dt_b_f   = (float*)(ws + 24576);    // 1536
    float* A_log_f  = (float*)(ws + 30720);    // 24576
    float* D_f      = (float*)(ws + 129024);   // 1536
    float* xproj_f  = (float*)(ws + 135168);   // 49152
    unsigned short* xb    = (unsigned short*)(ws + 524288);    // [4096][768]  (dead after gemm1)
    unsigned short* inT   = (unsigned short*)(ws + 6815744);   // [3072][768]  (dead after gemm1)
    unsigned short* yg    = (unsigned short*)(ws + 524288);    // [4096][1536] alias xb+inT
    unsigned short* dtT   = (unsigned short*)(ws + 13107200);  // [1536][1536]
    unsigned short* outT  = (unsigned short*)(ws + 17825792);  // [768][1536]
    unsigned short* xcpre = (unsigned short*)(ws + 20185088);  // [4096][1536] (dead after conv)
    unsigned short* dlt   = xcpre;                             // alias (gemm2 out)
    float*          BC    = (float*)(ws + 32768000);           // [4096][32]
    unsigned short* zg    = (unsigned short*)(ws + 33292288);  // [4096][1536] silu(z)
    unsigned short* xcb   = (unsigned short*)(ws + 45875200);  // [4096][1536]
    float*          scanS = (float*)(ws + 58458112);           // [2][32][1536][16] f32 6.29MB
    unsigned short* scanP = (unsigned short*)(ws + 64749568);  // same shape bf16   3.15MB
                                                               // high-water 67895296

    cvt_params_kernel<<<324, 256, 0, stream>>>(conv_w, conv_b, dt_b, A_log, Dvec, xproj_w,
                                               (float*)ws);
    cvt_x_kernel<<<3072, 256, 0, stream>>>(x, xb);
    transpose_any<<<dim3(3072 / 32, 768 / 32), 256, 0, stream>>>(in_w, inT, 768, 3072);
    transpose_any<<<dim3(1536 / 32, 1536 / 32), 256, 0, stream>>>(dt_w, dtT, 1536, 1536);
    transpose_any<<<dim3(768 / 32, 1536 / 32), 256, 0, stream>>>(out_w, outT, 1536, 768);

    gemm_kernel<3><<<dim3(32, 24), 256, 0, stream>>>(xb, inT, (void*)xcpre, (void*)zg,
                                                     nullptr, 4096, 3072, 768);
    conv_silu_kernel<<<(4096 * DINNER) / 256, 256, 0, stream>>>(xcpre, conv_w_f, conv_b_f, xcb);
    xproj_kernel<<<1024, 128, 0, stream>>>(xcb, xproj_f, BC);
    gemm_kernel<1><<<dim3(32, 12), 256, 0, stream>>>(xcb, dtT, (void*)dlt, nullptr,
                                                     dt_b_f, 4096, 1536, 1536);
    scan_phase_a<<<384, 256, 0, stream>>>(dlt, xcb, BC, A_log_f, scanP, scanS);
    scan_combine<<<192, 256, 0, stream>>>(scanP, scanS);
    scan_phase_c<<<384, 256, 0, stream>>>(dlt, xcb, BC, zg, A_log_f, D_f, scanS, yg);
    gemm_kernel<2><<<dim3(32, 6), 256, 0, stream>>>(yg, outT, d_out, nullptr,
                                                    nullptr, 4096, 768, 1536);
}

// Round 12
// 429.822 us; speedup vs baseline: 1.2267x; 1.0145x over previous
//
#include <hip/hip_runtime.h>
#include <cmath>

// SimplifiedSSM: B=2, L=2048, d_model=768, d_state=16, d_inner=1536
// ROUND 12: GEMM staging via async global_load_lds (16B) — removes the
// global->VGPR->ds_write round-trip (m93->m97 ladder step). Unpadded LDS
// tile (stride 32 shorts) as required by the lane*16B landing contract.
#define DMODEL 768
#define DINNER 1536
#define NSTATE 16
#define SEQL   2048
#define NCHUNK 32
#define CHLEN  64      // SEQL / NCHUNK

#define DT_F32  0
#define DT_BF16 1
#define DT_ZERO 2

typedef __bf16 bf16x8 __attribute__((ext_vector_type(8)));
typedef float  f32x4  __attribute__((ext_vector_type(4)));

typedef __attribute__((address_space(3))) unsigned short lds_us;
typedef const __attribute__((address_space(1))) unsigned short glob_us;

__device__ __forceinline__ void async_cp16(glob_us* g, lds_us* l) {
    __builtin_amdgcn_global_load_lds((const __attribute__((address_space(1))) void*)g,
                                     (__attribute__((address_space(3))) void*)l, 16, 0, 0);
}

__device__ __forceinline__ float bf2f(unsigned short h) {
    union { unsigned u; float f; } v; v.u = ((unsigned)h) << 16; return v.f;
}
__device__ __forceinline__ unsigned short f2bf(float f) {
    union { float f; unsigned u; } v; v.f = f;
    unsigned r = (v.u + 0x7FFFu + ((v.u >> 16) & 1u)) >> 16;
    return (unsigned short)r;
}
__device__ int detect_dtype(const void* p) {
    const unsigned* u = (const unsigned*)p;
    int nzlo = 0, band = 0, anynz = 0;
    for (int i = 0; i < 64; ++i) {
        unsigned w = u[i];
        anynz |= (w != 0);
        unsigned lo = w & 0xFFFFu;
        if (lo) {
            ++nzlo;
            unsigned e8 = (lo >> 7) & 0xFF;
            if (e8 >= 0x60 && e8 <= 0x8E) ++band;
        }
    }
    if (nzlo >= 8) return (band * 2 > nzlo) ? DT_BF16 : DT_F32;
    return anynz ? DT_F32 : DT_ZERO;
}
__device__ __forceinline__ float LD(const void* p, size_t i, int dt) {
    if (dt == DT_BF16) return bf2f(((const unsigned short*)p)[i]);
    if (dt == DT_F32)  return ((const float*)p)[i];
    return 0.f;
}

// ---- x -> bf16 ----
__global__ __launch_bounds__(256) void cvt_x_kernel(
    const void* __restrict__ x, unsigned short* __restrict__ xb)
{
    __shared__ int s_dt;
    if (threadIdx.x == 0) s_dt = detect_dtype(x);
    __syncthreads();
    const int dt = s_dt;
    size_t i = ((size_t)blockIdx.x * 256 + threadIdx.x) * 4;
    ushort4 o;
    o.x = f2bf(LD(x, i + 0, dt)); o.y = f2bf(LD(x, i + 1, dt));
    o.z = f2bf(LD(x, i + 2, dt)); o.w = f2bf(LD(x, i + 3, dt));
    *(ushort4*)&xb[i] = o;
}

// ---- small params -> f32 ----
__global__ __launch_bounds__(256) void cvt_params_kernel(
    const void* cw, const void* cb, const void* db, const void* Al,
    const void* Dv, const void* xp, float* __restrict__ out)
{
    __shared__ int dts[6];
    if (threadIdx.x == 0) {
        dts[0] = detect_dtype(cw); dts[1] = detect_dtype(cb);
        dts[2] = detect_dtype(db); dts[3] = detect_dtype(Al);
        dts[4] = detect_dtype(Dv); dts[5] = detect_dtype(xp);
    }
    __syncthreads();
    int g = blockIdx.x * 256 + threadIdx.x;
    if (g >= 82944) return;
    const void* src; int local; int which;
    if      (g <  4608) { src = cw; local = g;         which = 0; }
    else if (g <  6144) { src = cb; local = g - 4608;  which = 1; }
    else if (g <  7680) { src = db; local = g - 6144;  which = 2; }
    else if (g < 32256) { src = Al; local = g - 7680;  which = 3; }
    else if (g < 33792) { src = Dv; local = g - 32256; which = 4; }
    else                { src = xp; local = g - 33792; which = 5; }
    out[g] = LD(src, local, dts[which]);
}

// ---- transpose: in[R][C] -> out[C][R] bf16 ----
__global__ __launch_bounds__(256) void transpose_any(
    const void* __restrict__ in, unsigned short* __restrict__ out, int R, int C)
{
    __shared__ unsigned short tile[32][33];
    __shared__ int s_dt;
    if (threadIdx.x == 0) s_dt = detect_dtype(in);
    __syncthreads();
    const int dt = s_dt;
    const int t = threadIdx.x;
    const int tx = t & 31, ty = t >> 5;
    const int bx = blockIdx.x * 32, by = blockIdx.y * 32;
    #pragma unroll
    for (int i = 0; i < 4; ++i) {
        int r = by + ty + i * 8;
        tile[ty + i * 8][tx] = f2bf(LD(in, (size_t)r * C + bx + tx, dt));
    }
    __syncthreads();
    #pragma unroll
    for (int i = 0; i < 4; ++i) {
        int c = bx + ty + i * 8;
        out[(size_t)c * R + by + tx] = tile[tx][ty + i * 8];
    }
}

// ---- MFMA GEMM: C = A[M][K] @ Bt[N][K]^T, async LDS staging ----
// EPI 1: bf16 C0 = softplus(v + biasf[col])
// EPI 2: f32  C0 = v (final output)
// EPI 3: col < N/2 -> bf16 C0 = v ; else bf16 C1 = silu(v)
template<int EPI>
__global__ __launch_bounds__(256) void gemm_kernel(
    const unsigned short* __restrict__ A, const unsigned short* __restrict__ Bt,
    void* __restrict__ C0, void* __restrict__ C1, const float* __restrict__ biasf,
    int M, int N, int K)
{
    __shared__ __align__(16) unsigned short As[128 * 32];
    __shared__ __align__(16) unsigned short Bs[128 * 32];
    const int t    = threadIdx.x;
    const int m0   = blockIdx.x * 128;
    const int n0   = blockIdx.y * 128;
    const int w    = t >> 6;
    const int lane = t & 63;
    const int wm   = (w >> 1) * 64, wn = (w & 1) * 64;
    const int lm   = lane & 15, quad = lane >> 4;
    const int lr   = lane >> 2;           // staging: row within 16-row group
    const int lc   = (lane & 3) * 8;      // staging: k-offset (shorts)

    f32x4 acc[4][4] = {};

    for (int k0 = 0; k0 < K; k0 += 32) {
        // async stage: wave w covers rows [w*32, w*32+32) of A and B tiles
        #pragma unroll
        for (int h = 0; h < 2; ++h) {
            int rb = w * 32 + h * 16;
            async_cp16((glob_us*)&A[(size_t)(m0 + rb + lr) * K + k0 + lc], (lds_us*)&As[rb * 32]);
            async_cp16((glob_us*)&Bt[(size_t)(n0 + rb + lr) * K + k0 + lc], (lds_us*)&Bs[rb * 32]);
        }
        __syncthreads();
        bf16x8 af[4], bfr[4];
        #pragma unroll
        for (int i = 0; i < 4; ++i)
            af[i] = *(const bf16x8*)&As[(wm + i * 16 + lm) * 32 + quad * 8];
        #pragma unroll
        for (int j = 0; j < 4; ++j)
            bfr[j] = *(const bf16x8*)&Bs[(wn + j * 16 + lm) * 32 + quad * 8];
        #pragma unroll
        for (int i = 0; i < 4; ++i)
            #pragma unroll
            for (int j = 0; j < 4; ++j)
                acc[i][j] = __builtin_amdgcn_mfma_f32_16x16x32_bf16(af[i], bfr[j], acc[i][j], 0, 0, 0);
        __syncthreads();
    }

    const int half = N >> 1;
    #pragma unroll
    for (int i = 0; i < 4; ++i) {
        #pragma unroll
        for (int j = 0; j < 4; ++j) {
            int col = n0 + wn + j * 16 + lm;
            #pragma unroll
            for (int r = 0; r < 4; ++r) {
                int row = m0 + wm + i * 16 + quad * 4 + r;
                float v = acc[i][j][r];
                if (EPI == 1) {
                    v += biasf[col];
                    float sp = (v > 20.f) ? v : log1pf(__expf(v));
                    ((unsigned short*)C0)[(size_t)row * N + col] = f2bf(sp);
                } else if (EPI == 2) {
                    ((float*)C0)[(size_t)row * N + col] = v;
                } else {
                    if (col < half) {
                        ((unsigned short*)C0)[(size_t)row * half + col] = f2bf(v);
                    } else {
                        float s = v / (1.f + __expf(-v));
                        ((unsigned short*)C1)[(size_t)row * half + col - half] = f2bf(s);
                    }
                }
            }
        }
    }
}

// ---- depthwise conv3 + bias + SiLU ----
__global__ __launch_bounds__(256) void conv_silu_kernel(
    const unsigned short* __restrict__ xcpre, const float* __restrict__ cwf,
    const float* __restrict__ cbf, unsigned short* __restrict__ xcb)
{
    int idx = blockIdx.x * 256 + threadIdx.x;
    int d   = idx % DINNER;
    int row = idx / DINNER;
    int l   = row % SEQL;
    size_t base = (size_t)row * DINNER + d;
    float acc = cbf[d];
    if (l > 0)        acc += bf2f(xcpre[base - DINNER]) * cwf[d * 3 + 0];
    acc += bf2f(xcpre[base]) * cwf[d * 3 + 1];
    if (l < SEQL - 1) acc += bf2f(xcpre[base + DINNER]) * cwf[d * 3 + 2];
    float s = acc / (1.f + __expf(-acc));
    xcb[base] = f2bf(s);
}

// ---- x_proj: BC[row][32] = xc[row][:] @ xproj_f[1536][32] ----
__global__ __launch_bounds__(128) void xproj_kernel(
    const unsigned short* __restrict__ xcb, const float* __restrict__ wf,
    float* __restrict__ BC)
{
    __shared__ float red[4][32][4];
    const int t = threadIdx.x;
    const int s = t & 31, part = t >> 5;
    const int row0 = blockIdx.x * 4;
    float acc[4] = {0.f, 0.f, 0.f, 0.f};
    for (int k = part * 384; k < (part + 1) * 384; ++k) {
        float wv = wf[k * 32 + s];
        #pragma unroll
        for (int r = 0; r < 4; ++r)
            acc[r] += bf2f(xcb[(size_t)(row0 + r) * DINNER + k]) * wv;
    }
    #pragma unroll
    for (int r = 0; r < 4; ++r) red[part][s][r] = acc[r];
    __syncthreads();
    if (t < 32) {
        #pragma unroll
        for (int r = 0; r < 4; ++r)
            BC[(size_t)(row0 + r) * 32 + t] =
                red[0][t][r] + red[1][t][r] + red[2][t][r] + red[3][t][r];
    }
}

// ================= register-state chunked scan (spill-free) =================
__global__ __launch_bounds__(256) void scan_phase_a(
    const unsigned short* __restrict__ dlt, const unsigned short* __restrict__ xcb,
    const float* __restrict__ BC, const float* __restrict__ A_log_f,
    unsigned short* __restrict__ P, float* __restrict__ S)
{
    int g = blockIdx.x * 256 + threadIdx.x;
    int d = g % DINNER;
    int c = (g / DINNER) % NCHUNK;
    int b = g / (DINNER * NCHUNK);
    f32x4 A4[4], h4[4];
    const f32x4* al4 = (const f32x4*)&A_log_f[d * 16];
    #pragma unroll
    for (int q = 0; q < 4; ++q) {
        f32x4 al = al4[q];
        f32x4 a;
        a[0] = -__expf(al[0]); a[1] = -__expf(al[1]);
        a[2] = -__expf(al[2]); a[3] = -__expf(al[3]);
        A4[q] = a;
        h4[q] = (f32x4){0.f, 0.f, 0.f, 0.f};
    }
    float sdv = 0.f;
    const int row0 = b * SEQL + c * CHLEN;
    for (int l = 0; l < CHLEN; ++l) {
        size_t row = (size_t)(row0 + l);
        float dv = bf2f(dlt[row * DINNER + d]);
        float xv = bf2f(xcb[row * DINNER + d]);
        float dx = dv * xv;
        sdv += dv;
        const f32x4* bc4 = (const f32x4*)&BC[row * 32];
        #pragma unroll
        for (int q = 0; q < 4; ++q) {
            f32x4 Bq = bc4[q];
            f32x4 e;
            e[0] = __expf(dv * A4[q][0]); e[1] = __expf(dv * A4[q][1]);
            e[2] = __expf(dv * A4[q][2]); e[3] = __expf(dv * A4[q][3]);
            h4[q] = e * h4[q] + dx * Bq;
        }
    }
    size_t idx = (((size_t)(b * NCHUNK + c)) * DINNER + d) * 16;
    #pragma unroll
    for (int q = 0; q < 4; ++q) {
        *(f32x4*)&S[idx + q * 4] = h4[q];
        ushort4 pq;
        pq.x = f2bf(__expf(sdv * A4[q][0]));
        pq.y = f2bf(__expf(sdv * A4[q][1]));
        pq.z = f2bf(__expf(sdv * A4[q][2]));
        pq.w = f2bf(__expf(sdv * A4[q][3]));
        *(ushort4*)&P[idx + q * 4] = pq;
    }
}

__global__ __launch_bounds__(256) void scan_combine(
    const unsigned short* __restrict__ P, float* __restrict__ S)
{
    int t = blockIdx.x * 256 + threadIdx.x;            // < 2*1536*16
    int b = t / (DINNER * NSTATE);
    int dn = t % (DINNER * NSTATE);
    float H = 0.f;
    for (int c = 0; c < NCHUNK; ++c) {
        size_t idx = ((size_t)(b * NCHUNK + c)) * (DINNER * NSTATE) + dn;
        float Pv = bf2f(P[idx]);
        float Sv = S[idx];
        S[idx] = H;                 // Hin for chunk c
        H = Pv * H + Sv;
    }
}

__global__ __launch_bounds__(256) void scan_phase_c(
    const unsigned short* __restrict__ dlt, const unsigned short* __restrict__ xcb,
    const float* __restrict__ BC, const unsigned short* __restrict__ zg,
    const float* __restrict__ A_log_f, const float* __restrict__ D_f,
    const float* __restrict__ Hin, unsigned short* __restrict__ yg)
{
    int g = blockIdx.x * 256 + threadIdx.x;
    int d = g % DINNER;
    int c = (g / DINNER) % NCHUNK;
    int b = g / (DINNER * NCHUNK);
    f32x4 A4[4], h4[4];
    const f32x4* al4 = (const f32x4*)&A_log_f[d * 16];
    size_t hidx = (((size_t)(b * NCHUNK + c)) * DINNER + d) * 16;
    const f32x4* hin4 = (const f32x4*)&Hin[hidx];
    #pragma unroll
    for (int q = 0; q < 4; ++q) {
        f32x4 al = al4[q];
        f32x4 a;
        a[0] = -__expf(al[0]); a[1] = -__expf(al[1]);
        a[2] = -__expf(al[2]); a[3] = -__expf(al[3]);
        A4[q] = a;
        h4[q] = hin4[q];
    }
    const float Dd = D_f[d];
    const int row0 = b * SEQL + c * CHLEN;
    for (int l = 0; l < CHLEN; ++l) {
        size_t row = (size_t)(row0 + l);
        float dv = bf2f(dlt[row * DINNER + d]);
        float xv = bf2f(xcb[row * DINNER + d]);
        float zv = bf2f(zg[row * DINNER + d]);
        float dx = dv * xv;
        const f32x4* bc4 = (const f32x4*)&BC[row * 32];
        f32x4 yv = (f32x4){0.f, 0.f, 0.f, 0.f};
        #pragma unroll
        for (int q = 0; q < 4; ++q) {
            f32x4 Bq = bc4[q];
            f32x4 Cq = bc4[4 + q];
            f32x4 e;
            e[0] = __expf(dv * A4[q][0]); e[1] = __expf(dv * A4[q][1]);
            e[2] = __expf(dv * A4[q][2]); e[3] = __expf(dv * A4[q][3]);
            h4[q] = e * h4[q] + dx * Bq;
            yv = yv + h4[q] * Cq;
        }
        float y = yv[0] + yv[1] + yv[2] + yv[3];
        yg[row * DINNER + d] = f2bf((y + Dd * xv) * zv);
    }
}

__global__ void guard_kernel(float* out, int code)
{
    if (threadIdx.x == 0 && blockIdx.x == 0 && code) out[0] = (float)code;
}

extern "C" void kernel_launch(void* const* d_in, const int* in_sizes, int n_in,
                              void* d_out, int out_size, void* d_ws, size_t ws_size,
                              hipStream_t stream) {
    static const int EXPECTED[10] = {3145728, 2359296, 4608, 1536, 49152,
                                     2359296, 1536, 24576, 1536, 1179648};
    bool ok = (n_in == 10);
    if (ok) for (int i = 0; i < 10; ++i) ok = ok && (in_sizes[i] == EXPECTED[i]);
    int code = 0;
    if (!ok) code = 2000;
    else if (ws_size < 67895296ULL) code = 3000;
    if (code) { guard_kernel<<<1, 64, 0, stream>>>((float*)d_out, code); return; }

    const void* x       = d_in[0];
    const void* in_w    = d_in[1];
    const void* conv_w  = d_in[2];
    const void* conv_b  = d_in[3];
    const void* xproj_w = d_in[4];
    const void* dt_w    = d_in[5];
    const void* dt_b    = d_in[6];
    const void* A_log   = d_in[7];
    const void* Dvec    = d_in[8];
    const void* out_w   = d_in[9];

    char* ws = (char*)d_ws;
    float* conv_w_f = (float*)(ws + 0);        // 4608
    float* conv_b_f = (float*)(ws + 18432);    // 1536
    float* dt_b_f   = (float*)(ws + 24576);    // 1536
    float* A_log_f  = (float*)(ws + 30720);    // 24576
    float* D_f      = (float*)(ws + 129024);   // 1536
    float* xproj_f  = (float*)(ws + 135168);   // 49152
    unsigned short* xb    = (unsigned short*)(ws + 524288);    // [4096][768]  (dead after gemm1)
    unsigned short* inT   = (unsigned short*)(ws + 6815744);   // [3072][768]  (dead after gemm1)
    unsigned short* yg    = (unsigned short*)(ws + 524288);    // [4096][1536] alias xb+inT
    unsigned short* dtT   = (unsigned short*)(ws + 13107200);  // [1536][1536]
    unsigned short* outT  = (unsigned short*)(ws + 17825792);  // [768][1536]
    unsigned short* xcpre = (unsigned short*)(ws + 20185088);  // [4096][1536] (dead after conv)
    unsigned short* dlt   = xcpre;                             // alias (gemm2 out)
    float*          BC    = (float*)(ws + 32768000);           // [4096][32]
    unsigned short* zg    = (unsigned short*)(ws + 33292288);  // [4096][1536] silu(z)
    unsigned short* xcb   = (unsigned short*)(ws + 45875200);  // [4096][1536]
    float*          scanS = (float*)(ws + 58458112);           // [2][32][1536][16] f32 6.29MB
    unsigned short* scanP = (unsigned short*)(ws + 64749568);  // same shape bf16   3.15MB

    cvt_params_kernel<<<324, 256, 0, stream>>>(conv_w, conv_b, dt_b, A_log, Dvec, xproj_w,
                                               (float*)ws);
    cvt_x_kernel<<<3072, 256, 0, stream>>>(x, xb);
    transpose_any<<<dim3(3072 / 32, 768 / 32), 256, 0, stream>>>(in_w, inT, 768, 3072);
    transpose_any<<<dim3(1536 / 32, 1536 / 32), 256, 0, stream>>>(dt_w, dtT, 1536, 1536);
    transpose_any<<<dim3(768 / 32, 1536 / 32), 256, 0, stream>>>(out_w, outT, 1536, 768);

    gemm_kernel<3><<<dim3(32, 24), 256, 0, stream>>>(xb, inT, (void*)xcpre, (void*)zg,
                                                     nullptr, 4096, 3072, 768);
    conv_silu_kernel<<<(4096 * DINNER) / 256, 256, 0, stream>>>(xcpre, conv_w_f, conv_b_f, xcb);
    xproj_kernel<<<1024, 128, 0, stream>>>(xcb, xproj_f, BC);
    gemm_kernel<1><<<dim3(32, 12), 256, 0, stream>>>(xcb, dtT, (void*)dlt, nullptr,
                                                     dt_b_f, 4096, 1536, 1536);
    scan_phase_a<<<384, 256, 0, stream>>>(dlt, xcb, BC, A_log_f, scanP, scanS);
    scan_combine<<<192, 256, 0, stream>>>(scanP, scanS);
    scan_phase_c<<<384, 256, 0, stream>>>(dlt, xcb, BC, zg, A_log_f, D_f, scanS, yg);
    gemm_kernel<2><<<dim3(32, 6), 256, 0, stream>>>(yg, outT, d_out, nullptr,
                                                    nullptr, 4096, 768, 1536);
}

// Round 13
// 408.979 us; speedup vs baseline: 1.2892x; 1.0510x over previous
//
#include <hip/hip_runtime.h>
#include <cmath>

// SimplifiedSSM: B=2, L=2048, d_model=768, d_state=16, d_inner=1536
// ROUND 13: GEMM retile 128x128 -> 128x64. R12 proved staging mechanics are
// not the GEMM bound; grids of 384/192 blocks (1.5/0.75 blocks/CU) are.
// 128x64 tiles double block counts into m97's ~3 blocks/CU overlap regime.
#define DMODEL 768
#define DINNER 1536
#define NSTATE 16
#define SEQL   2048
#define NCHUNK 32
#define CHLEN  64      // SEQL / NCHUNK

#define DT_F32  0
#define DT_BF16 1
#define DT_ZERO 2

typedef __bf16 bf16x8 __attribute__((ext_vector_type(8)));
typedef float  f32x4  __attribute__((ext_vector_type(4)));

typedef __attribute__((address_space(3))) unsigned short lds_us;
typedef const __attribute__((address_space(1))) unsigned short glob_us;

__device__ __forceinline__ void async_cp16(glob_us* g, lds_us* l) {
    __builtin_amdgcn_global_load_lds((const __attribute__((address_space(1))) void*)g,
                                     (__attribute__((address_space(3))) void*)l, 16, 0, 0);
}

__device__ __forceinline__ float bf2f(unsigned short h) {
    union { unsigned u; float f; } v; v.u = ((unsigned)h) << 16; return v.f;
}
__device__ __forceinline__ unsigned short f2bf(float f) {
    union { float f; unsigned u; } v; v.f = f;
    unsigned r = (v.u + 0x7FFFu + ((v.u >> 16) & 1u)) >> 16;
    return (unsigned short)r;
}
__device__ int detect_dtype(const void* p) {
    const unsigned* u = (const unsigned*)p;
    int nzlo = 0, band = 0, anynz = 0;
    for (int i = 0; i < 64; ++i) {
        unsigned w = u[i];
        anynz |= (w != 0);
        unsigned lo = w & 0xFFFFu;
        if (lo) {
            ++nzlo;
            unsigned e8 = (lo >> 7) & 0xFF;
            if (e8 >= 0x60 && e8 <= 0x8E) ++band;
        }
    }
    if (nzlo >= 8) return (band * 2 > nzlo) ? DT_BF16 : DT_F32;
    return anynz ? DT_F32 : DT_ZERO;
}
__device__ __forceinline__ float LD(const void* p, size_t i, int dt) {
    if (dt == DT_BF16) return bf2f(((const unsigned short*)p)[i]);
    if (dt == DT_F32)  return ((const float*)p)[i];
    return 0.f;
}

// ---- x -> bf16 ----
__global__ __launch_bounds__(256) void cvt_x_kernel(
    const void* __restrict__ x, unsigned short* __restrict__ xb)
{
    __shared__ int s_dt;
    if (threadIdx.x == 0) s_dt = detect_dtype(x);
    __syncthreads();
    const int dt = s_dt;
    size_t i = ((size_t)blockIdx.x * 256 + threadIdx.x) * 4;
    ushort4 o;
    o.x = f2bf(LD(x, i + 0, dt)); o.y = f2bf(LD(x, i + 1, dt));
    o.z = f2bf(LD(x, i + 2, dt)); o.w = f2bf(LD(x, i + 3, dt));
    *(ushort4*)&xb[i] = o;
}

// ---- small params -> f32 ----
__global__ __launch_bounds__(256) void cvt_params_kernel(
    const void* cw, const void* cb, const void* db, const void* Al,
    const void* Dv, const void* xp, float* __restrict__ out)
{
    __shared__ int dts[6];
    if (threadIdx.x == 0) {
        dts[0] = detect_dtype(cw); dts[1] = detect_dtype(cb);
        dts[2] = detect_dtype(db); dts[3] = detect_dtype(Al);
        dts[4] = detect_dtype(Dv); dts[5] = detect_dtype(xp);
    }
    __syncthreads();
    int g = blockIdx.x * 256 + threadIdx.x;
    if (g >= 82944) return;
    const void* src; int local; int which;
    if      (g <  4608) { src = cw; local = g;         which = 0; }
    else if (g <  6144) { src = cb; local = g - 4608;  which = 1; }
    else if (g <  7680) { src = db; local = g - 6144;  which = 2; }
    else if (g < 32256) { src = Al; local = g - 7680;  which = 3; }
    else if (g < 33792) { src = Dv; local = g - 32256; which = 4; }
    else                { src = xp; local = g - 33792; which = 5; }
    out[g] = LD(src, local, dts[which]);
}

// ---- transpose: in[R][C] -> out[C][R] bf16 ----
__global__ __launch_bounds__(256) void transpose_any(
    const void* __restrict__ in, unsigned short* __restrict__ out, int R, int C)
{
    __shared__ unsigned short tile[32][33];
    __shared__ int s_dt;
    if (threadIdx.x == 0) s_dt = detect_dtype(in);
    __syncthreads();
    const int dt = s_dt;
    const int t = threadIdx.x;
    const int tx = t & 31, ty = t >> 5;
    const int bx = blockIdx.x * 32, by = blockIdx.y * 32;
    #pragma unroll
    for (int i = 0; i < 4; ++i) {
        int r = by + ty + i * 8;
        tile[ty + i * 8][tx] = f2bf(LD(in, (size_t)r * C + bx + tx, dt));
    }
    __syncthreads();
    #pragma unroll
    for (int i = 0; i < 4; ++i) {
        int c = bx + ty + i * 8;
        out[(size_t)c * R + by + tx] = tile[tx][ty + i * 8];
    }
}

// ---- MFMA GEMM: C = A[M][K] @ Bt[N][K]^T, 128x64 tile, async LDS staging ----
// EPI 1: bf16 C0 = softplus(v + biasf[col])
// EPI 2: f32  C0 = v (final output)
// EPI 3: col < N/2 -> bf16 C0 = v ; else bf16 C1 = silu(v)
template<int EPI>
__global__ __launch_bounds__(256) void gemm_kernel(
    const unsigned short* __restrict__ A, const unsigned short* __restrict__ Bt,
    void* __restrict__ C0, void* __restrict__ C1, const float* __restrict__ biasf,
    int M, int N, int K)
{
    __shared__ __align__(16) unsigned short As[128 * 32];   // 8 KB
    __shared__ __align__(16) unsigned short Bs[64 * 32];    // 4 KB
    const int t    = threadIdx.x;
    const int m0   = blockIdx.x * 128;
    const int n0   = blockIdx.y * 64;
    const int w    = t >> 6;
    const int lane = t & 63;
    const int wm   = (w >> 1) * 64, wn = (w & 1) * 32;
    const int lm   = lane & 15, quad = lane >> 4;
    const int lr   = lane >> 2;           // staging: row within 16-row group
    const int lc   = (lane & 3) * 8;      // staging: k-offset (shorts)

    f32x4 acc[4][2] = {};

    for (int k0 = 0; k0 < K; k0 += 32) {
        // A: wave w stages rows [w*32, w*32+32); B: rows [w*16, w*16+16)
        #pragma unroll
        for (int h = 0; h < 2; ++h) {
            int rb = w * 32 + h * 16;
            async_cp16((glob_us*)&A[(size_t)(m0 + rb + lr) * K + k0 + lc], (lds_us*)&As[rb * 32]);
        }
        {
            int rb = w * 16;
            async_cp16((glob_us*)&Bt[(size_t)(n0 + rb + lr) * K + k0 + lc], (lds_us*)&Bs[rb * 32]);
        }
        __syncthreads();
        bf16x8 af[4], bfr[2];
        #pragma unroll
        for (int i = 0; i < 4; ++i)
            af[i] = *(const bf16x8*)&As[(wm + i * 16 + lm) * 32 + quad * 8];
        #pragma unroll
        for (int j = 0; j < 2; ++j)
            bfr[j] = *(const bf16x8*)&Bs[(wn + j * 16 + lm) * 32 + quad * 8];
        #pragma unroll
        for (int i = 0; i < 4; ++i)
            #pragma unroll
            for (int j = 0; j < 2; ++j)
                acc[i][j] = __builtin_amdgcn_mfma_f32_16x16x32_bf16(af[i], bfr[j], acc[i][j], 0, 0, 0);
        __syncthreads();
    }

    const int half = N >> 1;
    #pragma unroll
    for (int i = 0; i < 4; ++i) {
        #pragma unroll
        for (int j = 0; j < 2; ++j) {
            int col = n0 + wn + j * 16 + lm;
            #pragma unroll
            for (int r = 0; r < 4; ++r) {
                int row = m0 + wm + i * 16 + quad * 4 + r;
                float v = acc[i][j][r];
                if (EPI == 1) {
                    v += biasf[col];
                    float sp = (v > 20.f) ? v : log1pf(__expf(v));
                    ((unsigned short*)C0)[(size_t)row * N + col] = f2bf(sp);
                } else if (EPI == 2) {
                    ((float*)C0)[(size_t)row * N + col] = v;
                } else {
                    if (col < half) {
                        ((unsigned short*)C0)[(size_t)row * half + col] = f2bf(v);
                    } else {
                        float s = v / (1.f + __expf(-v));
                        ((unsigned short*)C1)[(size_t)row * half + col - half] = f2bf(s);
                    }
                }
            }
        }
    }
}

// ---- depthwise conv3 + bias + SiLU ----
__global__ __launch_bounds__(256) void conv_silu_kernel(
    const unsigned short* __restrict__ xcpre, const float* __restrict__ cwf,
    const float* __restrict__ cbf, unsigned short* __restrict__ xcb)
{
    int idx = blockIdx.x * 256 + threadIdx.x;
    int d   = idx % DINNER;
    int row = idx / DINNER;
    int l   = row % SEQL;
    size_t base = (size_t)row * DINNER + d;
    float acc = cbf[d];
    if (l > 0)        acc += bf2f(xcpre[base - DINNER]) * cwf[d * 3 + 0];
    acc += bf2f(xcpre[base]) * cwf[d * 3 + 1];
    if (l < SEQL - 1) acc += bf2f(xcpre[base + DINNER]) * cwf[d * 3 + 2];
    float s = acc / (1.f + __expf(-acc));
    xcb[base] = f2bf(s);
}

// ---- x_proj: BC[row][32] = xc[row][:] @ xproj_f[1536][32] ----
__global__ __launch_bounds__(128) void xproj_kernel(
    const unsigned short* __restrict__ xcb, const float* __restrict__ wf,
    float* __restrict__ BC)
{
    __shared__ float red[4][32][4];
    const int t = threadIdx.x;
    const int s = t & 31, part = t >> 5;
    const int row0 = blockIdx.x * 4;
    float acc[4] = {0.f, 0.f, 0.f, 0.f};
    for (int k = part * 384; k < (part + 1) * 384; ++k) {
        float wv = wf[k * 32 + s];
        #pragma unroll
        for (int r = 0; r < 4; ++r)
            acc[r] += bf2f(xcb[(size_t)(row0 + r) * DINNER + k]) * wv;
    }
    #pragma unroll
    for (int r = 0; r < 4; ++r) red[part][s][r] = acc[r];
    __syncthreads();
    if (t < 32) {
        #pragma unroll
        for (int r = 0; r < 4; ++r)
            BC[(size_t)(row0 + r) * 32 + t] =
                red[0][t][r] + red[1][t][r] + red[2][t][r] + red[3][t][r];
    }
}

// ================= register-state chunked scan (spill-free) =================
__global__ __launch_bounds__(256) void scan_phase_a(
    const unsigned short* __restrict__ dlt, const unsigned short* __restrict__ xcb,
    const float* __restrict__ BC, const float* __restrict__ A_log_f,
    unsigned short* __restrict__ P, float* __restrict__ S)
{
    int g = blockIdx.x * 256 + threadIdx.x;
    int d = g % DINNER;
    int c = (g / DINNER) % NCHUNK;
    int b = g / (DINNER * NCHUNK);
    f32x4 A4[4], h4[4];
    const f32x4* al4 = (const f32x4*)&A_log_f[d * 16];
    #pragma unroll
    for (int q = 0; q < 4; ++q) {
        f32x4 al = al4[q];
        f32x4 a;
        a[0] = -__expf(al[0]); a[1] = -__expf(al[1]);
        a[2] = -__expf(al[2]); a[3] = -__expf(al[3]);
        A4[q] = a;
        h4[q] = (f32x4){0.f, 0.f, 0.f, 0.f};
    }
    float sdv = 0.f;
    const int row0 = b * SEQL + c * CHLEN;
    for (int l = 0; l < CHLEN; ++l) {
        size_t row = (size_t)(row0 + l);
        float dv = bf2f(dlt[row * DINNER + d]);
        float xv = bf2f(xcb[row * DINNER + d]);
        float dx = dv * xv;
        sdv += dv;
        const f32x4* bc4 = (const f32x4*)&BC[row * 32];
        #pragma unroll
        for (int q = 0; q < 4; ++q) {
            f32x4 Bq = bc4[q];
            f32x4 e;
            e[0] = __expf(dv * A4[q][0]); e[1] = __expf(dv * A4[q][1]);
            e[2] = __expf(dv * A4[q][2]); e[3] = __expf(dv * A4[q][3]);
            h4[q] = e * h4[q] + dx * Bq;
        }
    }
    size_t idx = (((size_t)(b * NCHUNK + c)) * DINNER + d) * 16;
    #pragma unroll
    for (int q = 0; q < 4; ++q) {
        *(f32x4*)&S[idx + q * 4] = h4[q];
        ushort4 pq;
        pq.x = f2bf(__expf(sdv * A4[q][0]));
        pq.y = f2bf(__expf(sdv * A4[q][1]));
        pq.z = f2bf(__expf(sdv * A4[q][2]));
        pq.w = f2bf(__expf(sdv * A4[q][3]));
        *(ushort4*)&P[idx + q * 4] = pq;
    }
}

__global__ __launch_bounds__(256) void scan_combine(
    const unsigned short* __restrict__ P, float* __restrict__ S)
{
    int t = blockIdx.x * 256 + threadIdx.x;            // < 2*1536*16
    int b = t / (DINNER * NSTATE);
    int dn = t % (DINNER * NSTATE);
    float H = 0.f;
    for (int c = 0; c < NCHUNK; ++c) {
        size_t idx = ((size_t)(b * NCHUNK + c)) * (DINNER * NSTATE) + dn;
        float Pv = bf2f(P[idx]);
        float Sv = S[idx];
        S[idx] = H;                 // Hin for chunk c
        H = Pv * H + Sv;
    }
}

__global__ __launch_bounds__(256) void scan_phase_c(
    const unsigned short* __restrict__ dlt, const unsigned short* __restrict__ xcb,
    const float* __restrict__ BC, const unsigned short* __restrict__ zg,
    const float* __restrict__ A_log_f, const float* __restrict__ D_f,
    const float* __restrict__ Hin, unsigned short* __restrict__ yg)
{
    int g = blockIdx.x * 256 + threadIdx.x;
    int d = g % DINNER;
    int c = (g / DINNER) % NCHUNK;
    int b = g / (DINNER * NCHUNK);
    f32x4 A4[4], h4[4];
    const f32x4* al4 = (const f32x4*)&A_log_f[d * 16];
    size_t hidx = (((size_t)(b * NCHUNK + c)) * DINNER + d) * 16;
    const f32x4* hin4 = (const f32x4*)&Hin[hidx];
    #pragma unroll
    for (int q = 0; q < 4; ++q) {
        f32x4 al = al4[q];
        f32x4 a;
        a[0] = -__expf(al[0]); a[1] = -__expf(al[1]);
        a[2] = -__expf(al[2]); a[3] = -__expf(al[3]);
        A4[q] = a;
        h4[q] = hin4[q];
    }
    const float Dd = D_f[d];
    const int row0 = b * SEQL + c * CHLEN;
    for (int l = 0; l < CHLEN; ++l) {
        size_t row = (size_t)(row0 + l);
        float dv = bf2f(dlt[row * DINNER + d]);
        float xv = bf2f(xcb[row * DINNER + d]);
        float zv = bf2f(zg[row * DINNER + d]);
        float dx = dv * xv;
        const f32x4* bc4 = (const f32x4*)&BC[row * 32];
        f32x4 yv = (f32x4){0.f, 0.f, 0.f, 0.f};
        #pragma unroll
        for (int q = 0; q < 4; ++q) {
            f32x4 Bq = bc4[q];
            f32x4 Cq = bc4[4 + q];
            f32x4 e;
            e[0] = __expf(dv * A4[q][0]); e[1] = __expf(dv * A4[q][1]);
            e[2] = __expf(dv * A4[q][2]); e[3] = __expf(dv * A4[q][3]);
            h4[q] = e * h4[q] + dx * Bq;
            yv = yv + h4[q] * Cq;
        }
        float y = yv[0] + yv[1] + yv[2] + yv[3];
        yg[row * DINNER + d] = f2bf((y + Dd * xv) * zv);
    }
}

__global__ void guard_kernel(float* out, int code)
{
    if (threadIdx.x == 0 && blockIdx.x == 0 && code) out[0] = (float)code;
}

extern "C" void kernel_launch(void* const* d_in, const int* in_sizes, int n_in,
                              void* d_out, int out_size, void* d_ws, size_t ws_size,
                              hipStream_t stream) {
    static const int EXPECTED[10] = {3145728, 2359296, 4608, 1536, 49152,
                                     2359296, 1536, 24576, 1536, 1179648};
    bool ok = (n_in == 10);
    if (ok) for (int i = 0; i < 10; ++i) ok = ok && (in_sizes[i] == EXPECTED[i]);
    int code = 0;
    if (!ok) code = 2000;
    else if (ws_size < 67895296ULL) code = 3000;
    if (code) { guard_kernel<<<1, 64, 0, stream>>>((float*)d_out, code); return; }

    const void* x       = d_in[0];
    const void* in_w    = d_in[1];
    const void* conv_w  = d_in[2];
    const void* conv_b  = d_in[3];
    const void* xproj_w = d_in[4];
    const void* dt_w    = d_in[5];
    const void* dt_b    = d_in[6];
    const void* A_log   = d_in[7];
    const void* Dvec    = d_in[8];
    const void* out_w   = d_in[9];

    char* ws = (char*)d_ws;
    float* conv_w_f = (float*)(ws + 0);        // 4608
    float* conv_b_f = (float*)(ws + 18432);    // 1536
    float* dt_b_f   = (float*)(ws + 24576);    // 1536
    float* A_log_f  = (float*)(ws + 30720);    // 24576
    float* D_f      = (float*)(ws + 129024);   // 1536
    float* xproj_f  = (float*)(ws + 135168);   // 49152
    unsigned short* xb    = (unsigned short*)(ws + 524288);    // [4096][768]  (dead after gemm1)
    unsigned short* inT   = (unsigned short*)(ws + 6815744);   // [3072][768]  (dead after gemm1)
    unsigned short* yg    = (unsigned short*)(ws + 524288);    // [4096][1536] alias xb+inT
    unsigned short* dtT   = (unsigned short*)(ws + 13107200);  // [1536][1536]
    unsigned short* outT  = (unsigned short*)(ws + 17825792);  // [768][1536]
    unsigned short* xcpre = (unsigned short*)(ws + 20185088);  // [4096][1536] (dead after conv)
    unsigned short* dlt   = xcpre;                             // alias (gemm2 out)
    float*          BC    = (float*)(ws + 32768000);           // [4096][32]
    unsigned short* zg    = (unsigned short*)(ws + 33292288);  // [4096][1536] silu(z)
    unsigned short* xcb   = (unsigned short*)(ws + 45875200);  // [4096][1536]
    float*          scanS = (float*)(ws + 58458112);           // [2][32][1536][16] f32 6.29MB
    unsigned short* scanP = (unsigned short*)(ws + 64749568);  // same shape bf16   3.15MB

    cvt_params_kernel<<<324, 256, 0, stream>>>(conv_w, conv_b, dt_b, A_log, Dvec, xproj_w,
                                               (float*)ws);
    cvt_x_kernel<<<3072, 256, 0, stream>>>(x, xb);
    transpose_any<<<dim3(3072 / 32, 768 / 32), 256, 0, stream>>>(in_w, inT, 768, 3072);
    transpose_any<<<dim3(1536 / 32, 1536 / 32), 256, 0, stream>>>(dt_w, dtT, 1536, 1536);
    transpose_any<<<dim3(768 / 32, 1536 / 32), 256, 0, stream>>>(out_w, outT, 1536, 768);

    gemm_kernel<3><<<dim3(32, 48), 256, 0, stream>>>(xb, inT, (void*)xcpre, (void*)zg,
                                                     nullptr, 4096, 3072, 768);
    conv_silu_kernel<<<(4096 * DINNER) / 256, 256, 0, stream>>>(xcpre, conv_w_f, conv_b_f, xcb);
    xproj_kernel<<<1024, 128, 0, stream>>>(xcb, xproj_f, BC);
    gemm_kernel<1><<<dim3(32, 24), 256, 0, stream>>>(xcb, dtT, (void*)dlt, nullptr,
                                                     dt_b_f, 4096, 1536, 1536);
    scan_phase_a<<<384, 256, 0, stream>>>(dlt, xcb, BC, A_log_f, scanP, scanS);
    scan_combine<<<192, 256, 0, stream>>>(scanP, scanS);
    scan_phase_c<<<384, 256, 0, stream>>>(dlt, xcb, BC, zg, A_log_f, D_f, scanS, yg);
    gemm_kernel<2><<<dim3(32, 12), 256, 0, stream>>>(yg, outT, d_out, nullptr,
                                                    nullptr, 4096, 768, 1536);
}

// Round 14
// 371.547 us; speedup vs baseline: 1.4191x; 1.1007x over previous
//
#include <hip/hip_runtime.h>
#include <cmath>

// SimplifiedSSM: B=2, L=2048, d_model=768, d_state=16, d_inner=1536
// ROUND 14: (1) double-buffered async GEMM K-loop (1 barrier/iter, stage(k+1)
// issued after the barrier so its drain overlaps MFMA); (2) conflict-free LDS
// granule rotation (source-permuted async loads); (3) prep kernels merged 5->1.
#define DMODEL 768
#define DINNER 1536
#define NSTATE 16
#define SEQL   2048
#define NCHUNK 32
#define CHLEN  64      // SEQL / NCHUNK

#define DT_F32  0
#define DT_BF16 1
#define DT_ZERO 2

typedef __bf16 bf16x8 __attribute__((ext_vector_type(8)));
typedef float  f32x4  __attribute__((ext_vector_type(4)));

typedef __attribute__((address_space(3))) unsigned short lds_us;
typedef const __attribute__((address_space(1))) unsigned short glob_us;

__device__ __forceinline__ void async_cp16(glob_us* g, lds_us* l) {
    __builtin_amdgcn_global_load_lds((const __attribute__((address_space(1))) void*)g,
                                     (__attribute__((address_space(3))) void*)l, 16, 0, 0);
}

__device__ __forceinline__ float bf2f(unsigned short h) {
    union { unsigned u; float f; } v; v.u = ((unsigned)h) << 16; return v.f;
}
__device__ __forceinline__ unsigned short f2bf(float f) {
    union { float f; unsigned u; } v; v.f = f;
    unsigned r = (v.u + 0x7FFFu + ((v.u >> 16) & 1u)) >> 16;
    return (unsigned short)r;
}
__device__ int detect_dtype(const void* p) {
    const unsigned* u = (const unsigned*)p;
    int nzlo = 0, band = 0, anynz = 0;
    for (int i = 0; i < 64; ++i) {
        unsigned w = u[i];
        anynz |= (w != 0);
        unsigned lo = w & 0xFFFFu;
        if (lo) {
            ++nzlo;
            unsigned e8 = (lo >> 7) & 0xFF;
            if (e8 >= 0x60 && e8 <= 0x8E) ++band;
        }
    }
    if (nzlo >= 8) return (band * 2 > nzlo) ? DT_BF16 : DT_F32;
    return anynz ? DT_F32 : DT_ZERO;
}
__device__ __forceinline__ float LD(const void* p, size_t i, int dt) {
    if (dt == DT_BF16) return bf2f(((const unsigned short*)p)[i]);
    if (dt == DT_F32)  return ((const float*)p)[i];
    return 0.f;
}

// ---- fused prep: params->f32 | x->bf16 | 3 weight transposes ----
// blocks: [0,324) params, [324,3396) x, [3396,5700) in_w,
//         [5700,8004) dt_w, [8004,9156) out_w
__global__ __launch_bounds__(256) void prep_kernel(
    const void* __restrict__ x, const void* __restrict__ in_w,
    const void* __restrict__ cw, const void* __restrict__ cb,
    const void* __restrict__ xp, const void* __restrict__ dt_w,
    const void* __restrict__ db, const void* __restrict__ Al,
    const void* __restrict__ Dv, const void* __restrict__ out_w,
    unsigned short* __restrict__ xb, unsigned short* __restrict__ inT,
    unsigned short* __restrict__ dtT, unsigned short* __restrict__ outT,
    float* __restrict__ pf)
{
    __shared__ unsigned short tile[32][33];
    __shared__ int dts[6];
    const int blk = blockIdx.x;
    const int t   = threadIdx.x;

    if (blk < 324) {
        if (t == 0) {
            dts[0] = detect_dtype(cw); dts[1] = detect_dtype(cb);
            dts[2] = detect_dtype(db); dts[3] = detect_dtype(Al);
            dts[4] = detect_dtype(Dv); dts[5] = detect_dtype(xp);
        }
        __syncthreads();
        int g = blk * 256 + t;
        if (g >= 82944) return;
        const void* src; int local; int which;
        if      (g <  4608) { src = cw; local = g;         which = 0; }
        else if (g <  6144) { src = cb; local = g - 4608;  which = 1; }
        else if (g <  7680) { src = db; local = g - 6144;  which = 2; }
        else if (g < 32256) { src = Al; local = g - 7680;  which = 3; }
        else if (g < 33792) { src = Dv; local = g - 32256; which = 4; }
        else                { src = xp; local = g - 33792; which = 5; }
        pf[g] = LD(src, local, dts[which]);
    } else if (blk < 3396) {
        if (t == 0) dts[0] = detect_dtype(x);
        __syncthreads();
        const int dt = dts[0];
        size_t i = ((size_t)(blk - 324) * 256 + t) * 4;
        ushort4 o;
        o.x = f2bf(LD(x, i + 0, dt)); o.y = f2bf(LD(x, i + 1, dt));
        o.z = f2bf(LD(x, i + 2, dt)); o.w = f2bf(LD(x, i + 3, dt));
        *(ushort4*)&xb[i] = o;
    } else {
        const void* src; unsigned short* dst; int R, C, tx_n, idx;
        if (blk < 5700)      { src = in_w;  dst = inT;  R = 768;  C = 3072; tx_n = 96; idx = blk - 3396; }
        else if (blk < 8004) { src = dt_w;  dst = dtT;  R = 1536; C = 1536; tx_n = 48; idx = blk - 5700; }
        else                 { src = out_w; dst = outT; R = 1536; C = 768;  tx_n = 24; idx = blk - 8004; }
        if (t == 0) dts[0] = detect_dtype(src);
        __syncthreads();
        const int dt = dts[0];
        const int tx = t & 31, ty = t >> 5;
        const int bx = (idx % tx_n) * 32, by = (idx / tx_n) * 32;
        #pragma unroll
        for (int i = 0; i < 4; ++i) {
            int r = by + ty + i * 8;
            tile[ty + i * 8][tx] = f2bf(LD(src, (size_t)r * C + bx + tx, dt));
        }
        __syncthreads();
        #pragma unroll
        for (int i = 0; i < 4; ++i) {
            int c = bx + ty + i * 8;
            dst[(size_t)c * R + by + tx] = tile[tx][ty + i * 8];
        }
    }
}

// ---- MFMA GEMM: C = A[M][K] @ Bt[N][K]^T, 128x64 tile, double-buffered async ----
// LDS granule rotation: slot (row, g) holds k-granule (g - (row>>1)) & 3.
// EPI 1: bf16 C0 = softplus(v + biasf[col])
// EPI 2: f32  C0 = v (final output)
// EPI 3: col < N/2 -> bf16 C0 = v ; else bf16 C1 = silu(v)
template<int EPI>
__global__ __launch_bounds__(256) void gemm_kernel(
    const unsigned short* __restrict__ A, const unsigned short* __restrict__ Bt,
    void* __restrict__ C0, void* __restrict__ C1, const float* __restrict__ biasf,
    int M, int N, int K)
{
    __shared__ __align__(16) unsigned short As[2][128 * 32];   // 16 KB
    __shared__ __align__(16) unsigned short Bs[2][64 * 32];    // 8 KB
    const int t    = threadIdx.x;
    const int m0   = blockIdx.x * 128;
    const int n0   = blockIdx.y * 64;
    const int w    = t >> 6;
    const int lane = t & 63;
    const int wm   = (w >> 1) * 64, wn = (w & 1) * 32;
    const int lm   = lane & 15, quad = lane >> 4;
    const int srow = lane >> 2;          // staging: row within 16-row group
    const int sg   = lane & 3;           // staging: granule slot

    f32x4 acc[4][2] = {};

    // prologue: stage k0=0 into buffer 0
    #pragma unroll
    for (int h = 0; h < 2; ++h) {
        int row = w * 32 + h * 16 + srow;
        int kg  = (sg - (row >> 1)) & 3;
        async_cp16((glob_us*)&A[(size_t)(m0 + row) * K + kg * 8],
                   (lds_us*)&As[0][(w * 32 + h * 16) * 32]);
    }
    {
        int brow = w * 16 + srow;
        int bkg  = (sg - (brow >> 1)) & 3;
        async_cp16((glob_us*)&Bt[(size_t)(n0 + brow) * K + bkg * 8],
                   (lds_us*)&Bs[0][(w * 16) * 32]);
    }

    int p = 0;
    for (int k0 = 0; k0 < K; k0 += 32) {
        __syncthreads();                       // drains stage(k0); reads of buf p^1 long done
        if (k0 + 32 < K) {                     // stage k0+32 into the other buffer (overlaps MFMA)
            #pragma unroll
            for (int h = 0; h < 2; ++h) {
                int row = w * 32 + h * 16 + srow;
                int kg  = (sg - (row >> 1)) & 3;
                async_cp16((glob_us*)&A[(size_t)(m0 + row) * K + k0 + 32 + kg * 8],
                           (lds_us*)&As[p ^ 1][(w * 32 + h * 16) * 32]);
            }
            int brow = w * 16 + srow;
            int bkg  = (sg - (brow >> 1)) & 3;
            async_cp16((glob_us*)&Bt[(size_t)(n0 + brow) * K + k0 + 32 + bkg * 8],
                       (lds_us*)&Bs[p ^ 1][(w * 16) * 32]);
        }
        bf16x8 af[4], bfr[2];
        #pragma unroll
        for (int i = 0; i < 4; ++i) {
            int row = wm + i * 16 + lm;
            int g   = (quad + (row >> 1)) & 3;
            af[i] = *(const bf16x8*)&As[p][row * 32 + g * 8];
        }
        #pragma unroll
        for (int j = 0; j < 2; ++j) {
            int row = wn + j * 16 + lm;
            int g   = (quad + (row >> 1)) & 3;
            bfr[j] = *(const bf16x8*)&Bs[p][row * 32 + g * 8];
        }
        #pragma unroll
        for (int i = 0; i < 4; ++i)
            #pragma unroll
            for (int j = 0; j < 2; ++j)
                acc[i][j] = __builtin_amdgcn_mfma_f32_16x16x32_bf16(af[i], bfr[j], acc[i][j], 0, 0, 0);
        p ^= 1;
    }

    const int half = N >> 1;
    #pragma unroll
    for (int i = 0; i < 4; ++i) {
        #pragma unroll
        for (int j = 0; j < 2; ++j) {
            int col = n0 + wn + j * 16 + lm;
            #pragma unroll
            for (int r = 0; r < 4; ++r) {
                int row = m0 + wm + i * 16 + quad * 4 + r;
                float v = acc[i][j][r];
                if (EPI == 1) {
                    v += biasf[col];
                    float sp = (v > 20.f) ? v : log1pf(__expf(v));
                    ((unsigned short*)C0)[(size_t)row * N + col] = f2bf(sp);
                } else if (EPI == 2) {
                    ((float*)C0)[(size_t)row * N + col] = v;
                } else {
                    if (col < half) {
                        ((unsigned short*)C0)[(size_t)row * half + col] = f2bf(v);
                    } else {
                        float s = v / (1.f + __expf(-v));
                        ((unsigned short*)C1)[(size_t)row * half + col - half] = f2bf(s);
                    }
                }
            }
        }
    }
}

// ---- depthwise conv3 + bias + SiLU ----
__global__ __launch_bounds__(256) void conv_silu_kernel(
    const unsigned short* __restrict__ xcpre, const float* __restrict__ cwf,
    const float* __restrict__ cbf, unsigned short* __restrict__ xcb)
{
    int idx = blockIdx.x * 256 + threadIdx.x;
    int d   = idx % DINNER;
    int row = idx / DINNER;
    int l   = row % SEQL;
    size_t base = (size_t)row * DINNER + d;
    float acc = cbf[d];
    if (l > 0)        acc += bf2f(xcpre[base - DINNER]) * cwf[d * 3 + 0];
    acc += bf2f(xcpre[base]) * cwf[d * 3 + 1];
    if (l < SEQL - 1) acc += bf2f(xcpre[base + DINNER]) * cwf[d * 3 + 2];
    float s = acc / (1.f + __expf(-acc));
    xcb[base] = f2bf(s);
}

// ---- x_proj: BC[row][32] = xc[row][:] @ xproj_f[1536][32] ----
__global__ __launch_bounds__(128) void xproj_kernel(
    const unsigned short* __restrict__ xcb, const float* __restrict__ wf,
    float* __restrict__ BC)
{
    __shared__ float red[4][32][4];
    const int t = threadIdx.x;
    const int s = t & 31, part = t >> 5;
    const int row0 = blockIdx.x * 4;
    float acc[4] = {0.f, 0.f, 0.f, 0.f};
    for (int k = part * 384; k < (part + 1) * 384; ++k) {
        float wv = wf[k * 32 + s];
        #pragma unroll
        for (int r = 0; r < 4; ++r)
            acc[r] += bf2f(xcb[(size_t)(row0 + r) * DINNER + k]) * wv;
    }
    #pragma unroll
    for (int r = 0; r < 4; ++r) red[part][s][r] = acc[r];
    __syncthreads();
    if (t < 32) {
        #pragma unroll
        for (int r = 0; r < 4; ++r)
            BC[(size_t)(row0 + r) * 32 + t] =
                red[0][t][r] + red[1][t][r] + red[2][t][r] + red[3][t][r];
    }
}

// ================= register-state chunked scan (spill-free) =================
__global__ __launch_bounds__(256) void scan_phase_a(
    const unsigned short* __restrict__ dlt, const unsigned short* __restrict__ xcb,
    const float* __restrict__ BC, const float* __restrict__ A_log_f,
    unsigned short* __restrict__ P, float* __restrict__ S)
{
    int g = blockIdx.x * 256 + threadIdx.x;
    int d = g % DINNER;
    int c = (g / DINNER) % NCHUNK;
    int b = g / (DINNER * NCHUNK);
    f32x4 A4[4], h4[4];
    const f32x4* al4 = (const f32x4*)&A_log_f[d * 16];
    #pragma unroll
    for (int q = 0; q < 4; ++q) {
        f32x4 al = al4[q];
        f32x4 a;
        a[0] = -__expf(al[0]); a[1] = -__expf(al[1]);
        a[2] = -__expf(al[2]); a[3] = -__expf(al[3]);
        A4[q] = a;
        h4[q] = (f32x4){0.f, 0.f, 0.f, 0.f};
    }
    float sdv = 0.f;
    const int row0 = b * SEQL + c * CHLEN;
    for (int l = 0; l < CHLEN; ++l) {
        size_t row = (size_t)(row0 + l);
        float dv = bf2f(dlt[row * DINNER + d]);
        float xv = bf2f(xcb[row * DINNER + d]);
        float dx = dv * xv;
        sdv += dv;
        const f32x4* bc4 = (const f32x4*)&BC[row * 32];
        #pragma unroll
        for (int q = 0; q < 4; ++q) {
            f32x4 Bq = bc4[q];
            f32x4 e;
            e[0] = __expf(dv * A4[q][0]); e[1] = __expf(dv * A4[q][1]);
            e[2] = __expf(dv * A4[q][2]); e[3] = __expf(dv * A4[q][3]);
            h4[q] = e * h4[q] + dx * Bq;
        }
    }
    size_t idx = (((size_t)(b * NCHUNK + c)) * DINNER + d) * 16;
    #pragma unroll
    for (int q = 0; q < 4; ++q) {
        *(f32x4*)&S[idx + q * 4] = h4[q];
        ushort4 pq;
        pq.x = f2bf(__expf(sdv * A4[q][0]));
        pq.y = f2bf(__expf(sdv * A4[q][1]));
        pq.z = f2bf(__expf(sdv * A4[q][2]));
        pq.w = f2bf(__expf(sdv * A4[q][3]));
        *(ushort4*)&P[idx + q * 4] = pq;
    }
}

__global__ __launch_bounds__(256) void scan_combine(
    const unsigned short* __restrict__ P, float* __restrict__ S)
{
    int t = blockIdx.x * 256 + threadIdx.x;            // < 2*1536*16
    int b = t / (DINNER * NSTATE);
    int dn = t % (DINNER * NSTATE);
    float H = 0.f;
    for (int c = 0; c < NCHUNK; ++c) {
        size_t idx = ((size_t)(b * NCHUNK + c)) * (DINNER * NSTATE) + dn;
        float Pv = bf2f(P[idx]);
        float Sv = S[idx];
        S[idx] = H;                 // Hin for chunk c
        H = Pv * H + Sv;
    }
}

__global__ __launch_bounds__(256) void scan_phase_c(
    const unsigned short* __restrict__ dlt, const unsigned short* __restrict__ xcb,
    const float* __restrict__ BC, const unsigned short* __restrict__ zg,
    const float* __restrict__ A_log_f, const float* __restrict__ D_f,
    const float* __restrict__ Hin, unsigned short* __restrict__ yg)
{
    int g = blockIdx.x * 256 + threadIdx.x;
    int d = g % DINNER;
    int c = (g / DINNER) % NCHUNK;
    int b = g / (DINNER * NCHUNK);
    f32x4 A4[4], h4[4];
    const f32x4* al4 = (const f32x4*)&A_log_f[d * 16];
    size_t hidx = (((size_t)(b * NCHUNK + c)) * DINNER + d) * 16;
    const f32x4* hin4 = (const f32x4*)&Hin[hidx];
    #pragma unroll
    for (int q = 0; q < 4; ++q) {
        f32x4 al = al4[q];
        f32x4 a;
        a[0] = -__expf(al[0]); a[1] = -__expf(al[1]);
        a[2] = -__expf(al[2]); a[3] = -__expf(al[3]);
        A4[q] = a;
        h4[q] = hin4[q];
    }
    const float Dd = D_f[d];
    const int row0 = b * SEQL + c * CHLEN;
    for (int l = 0; l < CHLEN; ++l) {
        size_t row = (size_t)(row0 + l);
        float dv = bf2f(dlt[row * DINNER + d]);
        float xv = bf2f(xcb[row * DINNER + d]);
        float zv = bf2f(zg[row * DINNER + d]);
        float dx = dv * xv;
        const f32x4* bc4 = (const f32x4*)&BC[row * 32];
        f32x4 yv = (f32x4){0.f, 0.f, 0.f, 0.f};
        #pragma unroll
        for (int q = 0; q < 4; ++q) {
            f32x4 Bq = bc4[q];
            f32x4 Cq = bc4[4 + q];
            f32x4 e;
            e[0] = __expf(dv * A4[q][0]); e[1] = __expf(dv * A4[q][1]);
            e[2] = __expf(dv * A4[q][2]); e[3] = __expf(dv * A4[q][3]);
            h4[q] = e * h4[q] + dx * Bq;
            yv = yv + h4[q] * Cq;
        }
        float y = yv[0] + yv[1] + yv[2] + yv[3];
        yg[row * DINNER + d] = f2bf((y + Dd * xv) * zv);
    }
}

__global__ void guard_kernel(float* out, int code)
{
    if (threadIdx.x == 0 && blockIdx.x == 0 && code) out[0] = (float)code;
}

extern "C" void kernel_launch(void* const* d_in, const int* in_sizes, int n_in,
                              void* d_out, int out_size, void* d_ws, size_t ws_size,
                              hipStream_t stream) {
    static const int EXPECTED[10] = {3145728, 2359296, 4608, 1536, 49152,
                                     2359296, 1536, 24576, 1536, 1179648};
    bool ok = (n_in == 10);
    if (ok) for (int i = 0; i < 10; ++i) ok = ok && (in_sizes[i] == EXPECTED[i]);
    int code = 0;
    if (!ok) code = 2000;
    else if (ws_size < 67895296ULL) code = 3000;
    if (code) { guard_kernel<<<1, 64, 0, stream>>>((float*)d_out, code); return; }

    const void* x       = d_in[0];
    const void* in_w    = d_in[1];
    const void* conv_w  = d_in[2];
    const void* conv_b  = d_in[3];
    const void* xproj_w = d_in[4];
    const void* dt_w    = d_in[5];
    const void* dt_b    = d_in[6];
    const void* A_log   = d_in[7];
    const void* Dvec    = d_in[8];
    const void* out_w   = d_in[9];

    char* ws = (char*)d_ws;
    float* conv_w_f = (float*)(ws + 0);        // 4608
    float* conv_b_f = (float*)(ws + 18432);    // 1536
    float* dt_b_f   = (float*)(ws + 24576);    // 1536
    float* A_log_f  = (float*)(ws + 30720);    // 24576
    float* D_f      = (float*)(ws + 129024);   // 1536
    float* xproj_f  = (float*)(ws + 135168);   // 49152
    unsigned short* xb    = (unsigned short*)(ws + 524288);    // [4096][768]  (dead after gemm1)
    unsigned short* inT   = (unsigned short*)(ws + 6815744);   // [3072][768]  (dead after gemm1)
    unsigned short* yg    = (unsigned short*)(ws + 524288);    // [4096][1536] alias xb+inT
    unsigned short* dtT   = (unsigned short*)(ws + 13107200);  // [1536][1536]
    unsigned short* outT  = (unsigned short*)(ws + 17825792);  // [768][1536]
    unsigned short* xcpre = (unsigned short*)(ws + 20185088);  // [4096][1536] (dead after conv)
    unsigned short* dlt   = xcpre;                             // alias (gemm2 out)
    float*          BC    = (float*)(ws + 32768000);           // [4096][32]
    unsigned short* zg    = (unsigned short*)(ws + 33292288);  // [4096][1536] silu(z)
    unsigned short* xcb   = (unsigned short*)(ws + 45875200);  // [4096][1536]
    float*          scanS = (float*)(ws + 58458112);           // [2][32][1536][16] f32 6.29MB
    unsigned short* scanP = (unsigned short*)(ws + 64749568);  // same shape bf16   3.15MB

    prep_kernel<<<9156, 256, 0, stream>>>(x, in_w, conv_w, conv_b, xproj_w, dt_w,
                                          dt_b, A_log, Dvec, out_w,
                                          xb, inT, dtT, outT, (float*)ws);

    gemm_kernel<3><<<dim3(32, 48), 256, 0, stream>>>(xb, inT, (void*)xcpre, (void*)zg,
                                                     nullptr, 4096, 3072, 768);
    conv_silu_kernel<<<(4096 * DINNER) / 256, 256, 0, stream>>>(xcpre, conv_w_f, conv_b_f, xcb);
    xproj_kernel<<<1024, 128, 0, stream>>>(xcb, xproj_f, BC);
    gemm_kernel<1><<<dim3(32, 24), 256, 0, stream>>>(xcb, dtT, (void*)dlt, nullptr,
                                                     dt_b_f, 4096, 1536, 1536);
    scan_phase_a<<<384, 256, 0, stream>>>(dlt, xcb, BC, A_log_f, scanP, scanS);
    scan_combine<<<192, 256, 0, stream>>>(scanP, scanS);
    scan_phase_c<<<384, 256, 0, stream>>>(dlt, xcb, BC, zg, A_log_f, D_f, scanS, yg);
    gemm_kernel<2><<<dim3(32, 12), 256, 0, stream>>>(yg, outT, d_out, nullptr,
                                                    nullptr, 4096, 768, 1536);
}